// Round 9
// baseline (587.872 us; speedup 1.0000x reference)
//
#include <hip/hip_runtime.h>
#include <hip/hip_bf16.h>

#define LSEQ   2048
#define DK     64
#define NH     16
#define BS     2
#define DMODEL 1024
#define BH     (BS*NH)    // 32
#define MTOT   (BS*LSEQ)  // 4096

typedef __attribute__((ext_vector_type(8))) short bf16x8;
typedef __attribute__((ext_vector_type(4))) float f32x4;
typedef __attribute__((ext_vector_type(16))) float f32x16;

#define MFMA16(a,b,c) __builtin_amdgcn_mfma_f32_16x16x32_bf16((a),(b),(c),0,0,0)
#define MFMA32(a,b,c) __builtin_amdgcn_mfma_f32_32x32x16_bf16((a),(b),(c),0,0,0)
#define GLD_LDS(g,l) __builtin_amdgcn_global_load_lds((const __attribute__((address_space(1))) void*)(g), (__attribute__((address_space(3))) void*)(l), 16, 0, 0)

__device__ __forceinline__ short f2bs(float f) {
  union { __hip_bfloat16 h; short s; } u; u.h = __float2bfloat16(f); return u.s;
}
__device__ __forceinline__ float b2f(unsigned short s) {
  union { unsigned u; float f; } v; v.u = ((unsigned)s) << 16; return v.f;
}
// cheap round-half-up bf16 (inputs guaranteed finite)
__device__ __forceinline__ unsigned short f2bs_c(float f) {
  union { float f; unsigned u; } v; v.f = f;
  return (unsigned short)((v.u + 0x8000u) >> 16);
}
__device__ __forceinline__ unsigned pk2c(float lo, float hi) {
  union { float f; unsigned u; } a, b; a.f = lo; b.f = hi;
  return ((a.u + 0x8000u) >> 16) | ((b.u + 0x8000u) & 0xffff0000u);
}
__device__ __forceinline__ unsigned pk2(float lo, float hi) {
  return (unsigned)(unsigned short)f2bs(lo) | (((unsigned)(unsigned short)f2bs(hi)) << 16);
}

// ---------------- f32 -> bf16 flat convert (vectorized) ----------------
__global__ __launch_bounds__(256) void cvt_bf16_k(const float* __restrict__ in,
                                                  short* __restrict__ out, int n8) {
  for (int i = blockIdx.x * blockDim.x + threadIdx.x; i < n8; i += gridDim.x * blockDim.x) {
    const float4* p = (const float4*)in + (size_t)i * 2;
    float4 a = p[0], b = p[1];
    uint4 o;
    o.x = pk2(a.x, a.y); o.y = pk2(a.z, a.w);
    o.z = pk2(b.x, b.y); o.w = pk2(b.z, b.w);
    ((uint4*)out)[i] = o;
  }
}

// ---------------- f32 [K][N] -> bf16 transposed [N][K] ----------------
__global__ __launch_bounds__(256) void cvt_tr_k(const float* __restrict__ W,
                                                short* __restrict__ Wt,
                                                int Krows, int Ncols) {
  __shared__ float tile[32][33];
  int n0 = blockIdx.x * 32, k0 = blockIdx.y * 32;
  int t = threadIdx.x;
#pragma unroll
  for (int i = 0; i < 4; ++i) {
    int idx = t + i * 256; int r = idx >> 5, c = idx & 31;
    tile[r][c] = W[(size_t)(k0 + r) * Ncols + n0 + c];
  }
  __syncthreads();
#pragma unroll
  for (int i = 0; i < 4; ++i) {
    int idx = t + i * 256; int r = idx >> 5, c = idx & 31;
    Wt[(size_t)(n0 + r) * Krows + k0 + c] = f2bs(tile[c][r]);
  }
}

// ---------------- 128x128-tile bf16 GEMM, K=1024 ----------------
__global__ __launch_bounds__(256) void gemm128_k(
    const short* __restrict__ A, const short* __restrict__ Bt,
    const float* __restrict__ bias, int mode,
    float* __restrict__ outF,
    short* __restrict__ Qb, short* __restrict__ Kb, short* __restrict__ VTb) {
  __shared__ short As[128 * 64];
  __shared__ short Bs[128 * 64];
  int tid = threadIdx.x, w = tid >> 6, ln = tid & 63, lg = ln >> 4, lr = ln & 15;
  int m0 = blockIdx.x * 128, n0 = blockIdx.y * 128;
  int wr = w >> 1, wc = w & 1;
  f32x4 acc[4][4] = {};

  for (int k0 = 0; k0 < 1024; k0 += 64) {
    __syncthreads();
#pragma unroll
    for (int i = 0; i < 4; ++i) {
      int cb = w * 64 + i * 256;
      int c = cb + ln;
      GLD_LDS(A  + (size_t)(m0 + (c >> 3)) * 1024 + k0 + (c & 7) * 8, &As[cb * 8]);
      GLD_LDS(Bt + (size_t)(n0 + (c >> 3)) * 1024 + k0 + (c & 7) * 8, &Bs[cb * 8]);
    }
    __syncthreads();
#pragma unroll
    for (int kh = 0; kh < 2; ++kh) {
      bf16x8 af[4], bfr[4];
#pragma unroll
      for (int mi = 0; mi < 4; ++mi)
        af[mi] = *(const bf16x8*)&As[(wr * 64 + mi * 16 + lr) * 64 + kh * 32 + lg * 8];
#pragma unroll
      for (int ni = 0; ni < 4; ++ni)
        bfr[ni] = *(const bf16x8*)&Bs[(wc * 64 + ni * 16 + lr) * 64 + kh * 32 + lg * 8];
#pragma unroll
      for (int mi = 0; mi < 4; ++mi)
#pragma unroll
        for (int ni = 0; ni < 4; ++ni)
          acc[mi][ni] = MFMA16(af[mi], bfr[ni], acc[mi][ni]);
    }
  }

#pragma unroll
  for (int ni = 0; ni < 4; ++ni) {
    int n = n0 + wc * 64 + ni * 16 + lr;
    float bv = bias[n];
    int part = n >> 10, cc = n & 1023, h = cc >> 6, dd = cc & 63;
#pragma unroll
    for (int mi = 0; mi < 4; ++mi) {
      int mbase = m0 + wr * 64 + mi * 16 + 4 * lg;
      float vv[4];
#pragma unroll
      for (int r = 0; r < 4; ++r) vv[r] = acc[mi][ni][r] + bv;
      if (mode == 1) {
#pragma unroll
        for (int r = 0; r < 4; ++r) outF[(size_t)(mbase + r) * 1024 + n] = vv[r];
      } else if (part == 2) {
        int b = mbase >> 11, tok = mbase & 2047, bh = b * NH + h;
        uint2 pk; pk.x = pk2c(vv[0], vv[1]); pk.y = pk2c(vv[2], vv[3]);
        *(uint2*)&VTb[((size_t)bh * DK + dd) * LSEQ + tok] = pk;
      } else {
        short* dst = (part == 0) ? Qb : Kb;
#pragma unroll
        for (int r = 0; r < 4; ++r) {
          int m = mbase + r;
          int b = m >> 11, tok = m & 2047, bh = b * NH + h;
          dst[((size_t)bh * LSEQ + tok) * DK + dd] = (short)f2bs_c(vv[r]);
        }
      }
    }
  }
}

// ---------------- per-row squared norms ----------------
__global__ __launch_bounds__(256) void norms_k(
    const short* __restrict__ Qm, const short* __restrict__ Qs,
    const short* __restrict__ Km, const short* __restrict__ Ks,
    float* __restrict__ sqq, float* __restrict__ sqk) {
  int id = blockIdx.x * 256 + threadIdx.x;  // 0..131071
  int row = id & 65535;
  const short* p1 = (id < 65536) ? Qm : Km;
  const short* p2 = (id < 65536) ? Qs : Ks;
  float* outp = (id < 65536) ? sqq : sqk;
  const uint4* a = (const uint4*)(p1 + (size_t)row * DK);
  const uint4* b = (const uint4*)(p2 + (size_t)row * DK);
  float s = 0.f;
#pragma unroll
  for (int i = 0; i < 8; ++i) {
    uint4 x = a[i], y = b[i];
    unsigned vx[4] = {x.x, x.y, x.z, x.w};
    unsigned vy[4] = {y.x, y.y, y.z, y.w};
#pragma unroll
    for (int j = 0; j < 4; ++j) {
      float l1 = b2f((unsigned short)(vx[j] & 0xffff)), h1 = b2f((unsigned short)(vx[j] >> 16));
      float l2 = b2f((unsigned short)(vy[j] & 0xffff)), h2 = b2f((unsigned short)(vy[j] >> 16));
      s += l1 * l1 + h1 * h1 + l2 * l2 + h2 * h2;
    }
  }
  outp[row] = s;
}

// ---------------- fused Wasserstein attention (32x32 MFMA, dbuf, 8 waves) ----------------
// grid (L/128, BH); 512 threads = 8 waves = (qg = w&3) x (ks = w>>2).
// Same wave-program as R8 (proven: 0 bank conflicts, pipelined staging);
// only change: 2x waves per block -> 16 waves/CU = 4 waves/SIMD so
// VALU/trans of one wave hides MFMA+LDS of others.
// Per tile: barrier (vmcnt drain -> tile t visible) -> issue gld_lds t+1
// into buf^1 -> compute tile t. Swizzle: LDS[row][s] = G[row][s ^ swz(row)],
// swz = (row&7) ^ ((row>>3)&3). P->PV B-frags via pk2c + permlane32_swap.
__global__ __launch_bounds__(512, 4) void attn_k(
    const short* __restrict__ Qm, const short* __restrict__ Km, const short* __restrict__ VmT,
    const short* __restrict__ Qs, const short* __restrict__ Ks, const short* __restrict__ VsT,
    const float* __restrict__ sqq, const float* __restrict__ sqk,
    short* __restrict__ Om, short* __restrict__ Os) {
  int bh = blockIdx.y;
  int q0 = blockIdx.x * 128;
  int tid = threadIdx.x, w = tid >> 6, ln = tid & 63;
  int l31 = ln & 31, h = ln >> 5;
  int qg = w & 3, ks = w >> 2;

  // buf layout (per 32KB half): [0,8K) Km [64 rows][64 sh] | [8K,16K) Ks
  // | [16K,32K) Vt [128 rows][64 sh]. Epilogue reuses [0,65536) + 1KB.
  __shared__ __align__(16) char pool[66560];
  short* poolS = (short*)pool;

  const size_t bhQ = (size_t)bh * LSEQ * DK;

  // Q fragments (B operand: col = q = l31, k-dim d = dblk*16 + h*8 + j)
  int q = q0 + qg * 32 + l31;
  bf16x8 qmf[4], qsf[4];
#pragma unroll
  for (int d = 0; d < 4; ++d) {
    qmf[d] = *(const bf16x8*)(Qm + bhQ + (size_t)q * DK + d * 16 + h * 8);
    qsf[d] = *(const bf16x8*)(Qs + bhQ + (size_t)q * DK + d * 16 + h * 8);
  }
  float sqQ = sqq[(size_t)bh * LSEQ + q];
  const float* sqkp = sqk + (size_t)bh * LSEQ;

  // staging: 32 wave-loads of 1KB per tile; wave w does j = w*4 + i (i<4).
  // LDS dest linear (slot j*1024B + lane*16B); global source col
  // pre-swizzled: cs = (ln&7) ^ (rr&7) ^ ((rr>>3)&3).
  const short* sb[4];
  int st[4];
#pragma unroll
  for (int i = 0; i < 4; ++i) {
    int j = w * 4 + i;
    int rr = j * 8 + (ln >> 3);
    int cs = ((ln & 7) ^ (rr & 7) ^ ((rr >> 3) & 3)) * 8;
    if (j < 8)       { sb[i] = Km + bhQ + (size_t)rr * DK + cs;                  st[i] = 64 * DK; }
    else if (j < 16) { sb[i] = Ks + bhQ + (size_t)(rr - 64) * DK + cs;           st[i] = 64 * DK; }
    else if (j < 24) { sb[i] = VmT + ((size_t)bh * DK + (rr - 128)) * LSEQ + cs; st[i] = 64; }
    else             { sb[i] = VsT + ((size_t)bh * DK + (rr - 192)) * LSEQ + cs; st[i] = 64; }
  }

  f32x16 acc[4] = {};
  float prs = 0.f;

  const int krow = ks * 32 + l31;
  const int kswz = ((krow & 7) ^ ((krow >> 3) & 3)) << 4;

  // prolog: issue tile 0 into buf 0
#pragma unroll
  for (int i = 0; i < 4; ++i)
    GLD_LDS(sb[i], poolS + (w * 4 + i) * 512);

  const int NT = LSEQ / 64;
  for (int t = 0; t < NT; ++t) {
    __syncthreads();   // drains vmcnt(0): tile t visible; prev buf reads done
    int cur = (t & 1) * 16384;           // shorts
    // issue loads for tile t+1 into the other buffer (fly during compute)
    if (t + 1 < NT) {
      int nxt = ((t + 1) & 1) * 16384;
#pragma unroll
      for (int i = 0; i < 4; ++i)
        GLD_LDS(sb[i] + (size_t)(t + 1) * st[i], poolS + nxt + (w * 4 + i) * 512);
    }
    const char* base = (const char*)(poolS + cur);

    // QK^T: S[k][q] for this wave's 32-k half, 32 q
    f32x16 sm = {}, ss = {};
#pragma unroll
    for (int d = 0; d < 4; ++d) {
      bf16x8 am = *(const bf16x8*)(base + krow * 128 + ((d * 32 + h * 16) ^ kswz));
      bf16x8 as = *(const bf16x8*)(base + 8192 + krow * 128 + ((d * 32 + h * 16) ^ kswz));
      sm = MFMA32(am, qmf[d], sm);
      ss = MFMA32(as, qsf[d], ss);
    }

    // softmax numerator; S row k_local = (reg&3) + 8*(reg>>2) + 4*h
    float pv[16];
    int k0b = t * 64 + ks * 32;
#pragma unroll
    for (int rq = 0; rq < 4; ++rq) {
      f32x4 rsk = *(const f32x4*)&sqkp[k0b + 8 * rq + 4 * h];
#pragma unroll
      for (int r = 0; r < 4; ++r) {
        int i = rq * 4 + r;
        float w2 = fmaf(-2.f, sm[i] + ss[i], sqQ + rsk[r]);
        float wd = __builtin_amdgcn_sqrtf(fmaxf(w2, 0.f));
        float sim = __expf(-wd);
        float p = __expf(sim);
        prs += p;
        pv[i] = p;
      }
    }
    // pack to bf16 + lane-half swap -> PV B-frags
    unsigned u0 = pk2c(pv[0], pv[1]),   u1 = pk2c(pv[2], pv[3]);
    unsigned u2 = pk2c(pv[4], pv[5]),   u3 = pk2c(pv[6], pv[7]);
    unsigned u4 = pk2c(pv[8], pv[9]),   u5 = pk2c(pv[10], pv[11]);
    unsigned u6 = pk2c(pv[12], pv[13]), u7 = pk2c(pv[14], pv[15]);
    asm volatile("v_permlane32_swap_b32 %0, %1" : "+v"(u0), "+v"(u2));
    asm volatile("v_permlane32_swap_b32 %0, %1" : "+v"(u1), "+v"(u3));
    asm volatile("v_permlane32_swap_b32 %0, %1" : "+v"(u4), "+v"(u6));
    asm volatile("v_permlane32_swap_b32 %0, %1" : "+v"(u5), "+v"(u7));
    union { uint4 u; bf16x8 v; } f0, f1;
    f0.u.x = u0; f0.u.y = u1; f0.u.z = u2; f0.u.w = u3;
    f1.u.x = u4; f1.u.y = u5; f1.u.z = u6; f1.u.w = u7;

    // PV: acc[vblk] += V-frag(32v x 16k) x P-frag
#pragma unroll
    for (int vblk = 0; vblk < 4; ++vblk) {
      int vrow = vblk * 32 + l31;
      int vswz = ((vrow & 7) ^ ((vrow >> 3) & 3)) << 4;
      const char* vbase = base + 16384 + vrow * 128;
      bf16x8 v0 = *(const bf16x8*)(vbase + ((ks * 64 + h * 16) ^ vswz));
      bf16x8 v1 = *(const bf16x8*)(vbase + ((ks * 64 + 32 + h * 16) ^ vswz));
      acc[vblk] = MFMA32(v0, f0.v, acc[vblk]);
      acc[vblk] = MFMA32(v1, f1.v, acc[vblk]);
    }
  }

  // row-sum: reduce over lane halves (k-coverage split by h)
  prs += __shfl_xor(prs, 32);

  // combine k-halves (ks=1 -> ks=0) through LDS scratch
  float* scr  = (float*)pool;             // [4 qg][4 vblk][4 rq][64 ln] f32x4 = 64 KB
  float* scrP = (float*)(pool + 65536);   // [4 qg][64 ln] f32 = 1 KB
  __syncthreads();
  if (ks == 1) {
#pragma unroll
    for (int vblk = 0; vblk < 4; ++vblk)
#pragma unroll
      for (int rq = 0; rq < 4; ++rq) {
        f32x4 qd;
        qd[0] = acc[vblk][rq * 4 + 0]; qd[1] = acc[vblk][rq * 4 + 1];
        qd[2] = acc[vblk][rq * 4 + 2]; qd[3] = acc[vblk][rq * 4 + 3];
        *(f32x4*)&scr[(((qg * 4 + vblk) * 4 + rq) * 64 + ln) * 4] = qd;
      }
    scrP[qg * 64 + ln] = prs;
  }
  __syncthreads();
  if (ks == 0) {
    float inv = 1.f / (prs + scrP[qg * 64 + ln]);
    int b = bh >> 4, hh = bh & 15;
    size_t orow = ((size_t)(b * LSEQ + q)) * DMODEL + hh * DK;
#pragma unroll
    for (int vblk = 0; vblk < 4; ++vblk) {
      short* obuf = (vblk < 2) ? Om : Os;
      int vbase = (vblk & 1) * 32 + 4 * h;
#pragma unroll
      for (int rq = 0; rq < 4; ++rq) {
        f32x4 od = *(const f32x4*)&scr[(((qg * 4 + vblk) * 4 + rq) * 64 + ln) * 4];
        float o0 = (acc[vblk][rq * 4 + 0] + od[0]) * inv;
        float o1 = (acc[vblk][rq * 4 + 1] + od[1]) * inv;
        float o2 = (acc[vblk][rq * 4 + 2] + od[2]) * inv;
        float o3 = (acc[vblk][rq * 4 + 3] + od[3]) * inv;
        uint2 pk; pk.x = pk2c(o0, o1); pk.y = pk2c(o2, o3);
        *(uint2*)(obuf + orow + vbase + 8 * rq) = pk;
      }
    }
  }
}

extern "C" void kernel_launch(void* const* d_in, const int* in_sizes, int n_in,
                              void* d_out, int out_size, void* d_ws, size_t ws_size,
                              hipStream_t stream) {
  const float* mu    = (const float*)d_in[0];
  const float* sigma = (const float*)d_in[1];
  const float* Wqm   = (const float*)d_in[2];
  const float* bqm   = (const float*)d_in[3];
  const float* Wqs   = (const float*)d_in[4];
  const float* bqs   = (const float*)d_in[5];
  const float* Wo    = (const float*)d_in[6];
  const float* bo    = (const float*)d_in[7];
  float* out = (float*)d_out;
  char* ws = (char*)d_ws;
  const size_t MB = 1u << 20;

  short* Amu   = (short*)(ws + 0);        // 8MB, reused as Om
  short* Asg   = (short*)(ws + 8 * MB);   // 8MB, reused as Os (contiguous with Om)
  short* Wqm_t = (short*)(ws + 16 * MB);  // 6MB
  short* Wqs_t = (short*)(ws + 22 * MB);  // 6MB
  short* Wo_t  = (short*)(ws + 28 * MB);  // 2MB
  short* Qm    = (short*)(ws + 30 * MB);  // 8MB each below
  short* Km    = (short*)(ws + 38 * MB);
  short* VmT   = (short*)(ws + 46 * MB);
  short* Qs    = (short*)(ws + 54 * MB);
  short* Ks    = (short*)(ws + 62 * MB);
  short* VsT   = (short*)(ws + 70 * MB);
  float* sqq   = (float*)(ws + 78 * MB);            // 256KB
  float* sqk   = (float*)(ws + 78 * MB + 256 * 1024);
  short* Om = Amu;
  short* Os = Asg;

  cvt_bf16_k<<<2048, 256, 0, stream>>>(mu, Amu, MTOT * DMODEL / 8);
  cvt_bf16_k<<<2048, 256, 0, stream>>>(sigma, Asg, MTOT * DMODEL / 8);
  cvt_tr_k<<<dim3(96, 32), 256, 0, stream>>>(Wqm, Wqm_t, 1024, 3072);
  cvt_tr_k<<<dim3(96, 32), 256, 0, stream>>>(Wqs, Wqs_t, 1024, 3072);
  cvt_tr_k<<<dim3(32, 32), 256, 0, stream>>>(Wo, Wo_t, 1024, 1024);

  gemm128_k<<<dim3(32, 24), 256, 0, stream>>>(Amu, Wqm_t, bqm, 0, nullptr, Qm, Km, VmT);
  gemm128_k<<<dim3(32, 24), 256, 0, stream>>>(Asg, Wqs_t, bqs, 0, nullptr, Qs, Ks, VsT);

  norms_k<<<512, 256, 0, stream>>>(Qm, Qs, Km, Ks, sqq, sqk);

  attn_k<<<dim3(LSEQ / 128, BH), 512, 0, stream>>>(Qm, Km, VmT, Qs, Ks, VsT, sqq, sqk, Om, Os);

  // out-proj for mu and sigma as ONE GEMM (Om|Os contiguous, M=8192)
  gemm128_k<<<dim3(64, 8), 256, 0, stream>>>(Om, Wo_t, bo, 1, out, nullptr, nullptr, nullptr);
}

// Round 10
// 284.384 us; speedup vs baseline: 2.0672x; 2.0672x over previous
//
#include <hip/hip_runtime.h>
#include <hip/hip_bf16.h>

#define LSEQ   2048
#define DK     64
#define NH     16
#define BS     2
#define DMODEL 1024
#define BH     (BS*NH)    // 32
#define MTOT   (BS*LSEQ)  // 4096

typedef __attribute__((ext_vector_type(8))) short bf16x8;
typedef __attribute__((ext_vector_type(4))) float f32x4;
typedef __attribute__((ext_vector_type(16))) float f32x16;

#define MFMA16(a,b,c) __builtin_amdgcn_mfma_f32_16x16x32_bf16((a),(b),(c),0,0,0)
#define MFMA32(a,b,c) __builtin_amdgcn_mfma_f32_32x32x16_bf16((a),(b),(c),0,0,0)
#define GLD_LDS(g,l) __builtin_amdgcn_global_load_lds((const __attribute__((address_space(1))) void*)(g), (__attribute__((address_space(3))) void*)(l), 16, 0, 0)

__device__ __forceinline__ short f2bs(float f) {
  union { __hip_bfloat16 h; short s; } u; u.h = __float2bfloat16(f); return u.s;
}
__device__ __forceinline__ float b2f(unsigned short s) {
  union { unsigned u; float f; } v; v.u = ((unsigned)s) << 16; return v.f;
}
// cheap round-half-up bf16 (inputs guaranteed finite)
__device__ __forceinline__ unsigned short f2bs_c(float f) {
  union { float f; unsigned u; } v; v.f = f;
  return (unsigned short)((v.u + 0x8000u) >> 16);
}
__device__ __forceinline__ unsigned pk2c(float lo, float hi) {
  union { float f; unsigned u; } a, b; a.f = lo; b.f = hi;
  return ((a.u + 0x8000u) >> 16) | ((b.u + 0x8000u) & 0xffff0000u);
}
__device__ __forceinline__ unsigned pk2(float lo, float hi) {
  return (unsigned)(unsigned short)f2bs(lo) | (((unsigned)(unsigned short)f2bs(hi)) << 16);
}

// ---------------- f32 -> bf16 flat convert (vectorized) ----------------
__global__ __launch_bounds__(256) void cvt_bf16_k(const float* __restrict__ in,
                                                  short* __restrict__ out, int n8) {
  for (int i = blockIdx.x * blockDim.x + threadIdx.x; i < n8; i += gridDim.x * blockDim.x) {
    const float4* p = (const float4*)in + (size_t)i * 2;
    float4 a = p[0], b = p[1];
    uint4 o;
    o.x = pk2(a.x, a.y); o.y = pk2(a.z, a.w);
    o.z = pk2(b.x, b.y); o.w = pk2(b.z, b.w);
    ((uint4*)out)[i] = o;
  }
}

// ---------------- f32 [K][N] -> bf16 transposed [N][K] ----------------
__global__ __launch_bounds__(256) void cvt_tr_k(const float* __restrict__ W,
                                                short* __restrict__ Wt,
                                                int Krows, int Ncols) {
  __shared__ float tile[32][33];
  int n0 = blockIdx.x * 32, k0 = blockIdx.y * 32;
  int t = threadIdx.x;
#pragma unroll
  for (int i = 0; i < 4; ++i) {
    int idx = t + i * 256; int r = idx >> 5, c = idx & 31;
    tile[r][c] = W[(size_t)(k0 + r) * Ncols + n0 + c];
  }
  __syncthreads();
#pragma unroll
  for (int i = 0; i < 4; ++i) {
    int idx = t + i * 256; int r = idx >> 5, c = idx & 31;
    Wt[(size_t)(n0 + r) * Krows + k0 + c] = f2bs(tile[c][r]);
  }
}

// ---------------- 128x128-tile bf16 GEMM, K=1024 ----------------
__global__ __launch_bounds__(256) void gemm128_k(
    const short* __restrict__ A, const short* __restrict__ Bt,
    const float* __restrict__ bias, int mode,
    float* __restrict__ outF,
    short* __restrict__ Qb, short* __restrict__ Kb, short* __restrict__ VTb) {
  __shared__ short As[128 * 64];
  __shared__ short Bs[128 * 64];
  int tid = threadIdx.x, w = tid >> 6, ln = tid & 63, lg = ln >> 4, lr = ln & 15;
  int m0 = blockIdx.x * 128, n0 = blockIdx.y * 128;
  int wr = w >> 1, wc = w & 1;
  f32x4 acc[4][4] = {};

  for (int k0 = 0; k0 < 1024; k0 += 64) {
    __syncthreads();
#pragma unroll
    for (int i = 0; i < 4; ++i) {
      int cb = w * 64 + i * 256;
      int c = cb + ln;
      GLD_LDS(A  + (size_t)(m0 + (c >> 3)) * 1024 + k0 + (c & 7) * 8, &As[cb * 8]);
      GLD_LDS(Bt + (size_t)(n0 + (c >> 3)) * 1024 + k0 + (c & 7) * 8, &Bs[cb * 8]);
    }
    __syncthreads();
#pragma unroll
    for (int kh = 0; kh < 2; ++kh) {
      bf16x8 af[4], bfr[4];
#pragma unroll
      for (int mi = 0; mi < 4; ++mi)
        af[mi] = *(const bf16x8*)&As[(wr * 64 + mi * 16 + lr) * 64 + kh * 32 + lg * 8];
#pragma unroll
      for (int ni = 0; ni < 4; ++ni)
        bfr[ni] = *(const bf16x8*)&Bs[(wc * 64 + ni * 16 + lr) * 64 + kh * 32 + lg * 8];
#pragma unroll
      for (int mi = 0; mi < 4; ++mi)
#pragma unroll
        for (int ni = 0; ni < 4; ++ni)
          acc[mi][ni] = MFMA16(af[mi], bfr[ni], acc[mi][ni]);
    }
  }

#pragma unroll
  for (int ni = 0; ni < 4; ++ni) {
    int n = n0 + wc * 64 + ni * 16 + lr;
    float bv = bias[n];
    int part = n >> 10, cc = n & 1023, h = cc >> 6, dd = cc & 63;
#pragma unroll
    for (int mi = 0; mi < 4; ++mi) {
      int mbase = m0 + wr * 64 + mi * 16 + 4 * lg;
      float vv[4];
#pragma unroll
      for (int r = 0; r < 4; ++r) vv[r] = acc[mi][ni][r] + bv;
      if (mode == 1) {
#pragma unroll
        for (int r = 0; r < 4; ++r) outF[(size_t)(mbase + r) * 1024 + n] = vv[r];
      } else if (part == 2) {
        int b = mbase >> 11, tok = mbase & 2047, bh = b * NH + h;
        uint2 pk; pk.x = pk2c(vv[0], vv[1]); pk.y = pk2c(vv[2], vv[3]);
        *(uint2*)&VTb[((size_t)bh * DK + dd) * LSEQ + tok] = pk;
      } else {
        short* dst = (part == 0) ? Qb : Kb;
#pragma unroll
        for (int r = 0; r < 4; ++r) {
          int m = mbase + r;
          int b = m >> 11, tok = m & 2047, bh = b * NH + h;
          dst[((size_t)bh * LSEQ + tok) * DK + dd] = (short)f2bs_c(vv[r]);
        }
      }
    }
  }
}

// ---------------- per-row squared norms ----------------
__global__ __launch_bounds__(256) void norms_k(
    const short* __restrict__ Qm, const short* __restrict__ Qs,
    const short* __restrict__ Km, const short* __restrict__ Ks,
    float* __restrict__ sqq, float* __restrict__ sqk) {
  int id = blockIdx.x * 256 + threadIdx.x;  // 0..131071
  int row = id & 65535;
  const short* p1 = (id < 65536) ? Qm : Km;
  const short* p2 = (id < 65536) ? Qs : Ks;
  float* outp = (id < 65536) ? sqq : sqk;
  const uint4* a = (const uint4*)(p1 + (size_t)row * DK);
  const uint4* b = (const uint4*)(p2 + (size_t)row * DK);
  float s = 0.f;
#pragma unroll
  for (int i = 0; i < 8; ++i) {
    uint4 x = a[i], y = b[i];
    unsigned vx[4] = {x.x, x.y, x.z, x.w};
    unsigned vy[4] = {y.x, y.y, y.z, y.w};
#pragma unroll
    for (int j = 0; j < 4; ++j) {
      float l1 = b2f((unsigned short)(vx[j] & 0xffff)), h1 = b2f((unsigned short)(vx[j] >> 16));
      float l2 = b2f((unsigned short)(vy[j] & 0xffff)), h2 = b2f((unsigned short)(vy[j] >> 16));
      s += l1 * l1 + h1 * h1 + l2 * l2 + h2 * h2;
    }
  }
  outp[row] = s;
}

// ---------------- fused Wasserstein attention (32x32 MFMA, dbuf, 8 waves) ----------------
// grid (L/128, BH); 512 threads = 8 waves = (qg = w&3) x (ks = w>>2).
// Same wave-program as R8 (0 bank conflicts, pipelined dbuf staging).
// __launch_bounds__(512, 2): HIP 2nd arg = min BLOCKS/CU (CUDA semantics!)
// -> 2 blocks/CU = 16 waves/CU = 4 waves/SIMD, VGPR cap 128 (fits ~104,
// NO spill). (512,4) would cap at 64 VGPR and spill -- R4/R5/R9 evidence.
__global__ __launch_bounds__(512, 2) void attn_k(
    const short* __restrict__ Qm, const short* __restrict__ Km, const short* __restrict__ VmT,
    const short* __restrict__ Qs, const short* __restrict__ Ks, const short* __restrict__ VsT,
    const float* __restrict__ sqq, const float* __restrict__ sqk,
    short* __restrict__ Om, short* __restrict__ Os) {
  int bh = blockIdx.y;
  int q0 = blockIdx.x * 128;
  int tid = threadIdx.x, w = tid >> 6, ln = tid & 63;
  int l31 = ln & 31, h = ln >> 5;
  int qg = w & 3, ks = w >> 2;

  // buf layout (per 32KB half): [0,8K) Km [64 rows][64 sh] | [8K,16K) Ks
  // | [16K,32K) Vt [128 rows][64 sh]. Epilogue reuses [0,65536) + 1KB.
  __shared__ __align__(16) char pool[66560];
  short* poolS = (short*)pool;

  const size_t bhQ = (size_t)bh * LSEQ * DK;

  // Q fragments (B operand: col = q = l31, k-dim d = dblk*16 + h*8 + j)
  int q = q0 + qg * 32 + l31;
  bf16x8 qmf[4], qsf[4];
#pragma unroll
  for (int d = 0; d < 4; ++d) {
    qmf[d] = *(const bf16x8*)(Qm + bhQ + (size_t)q * DK + d * 16 + h * 8);
    qsf[d] = *(const bf16x8*)(Qs + bhQ + (size_t)q * DK + d * 16 + h * 8);
  }
  float sqQ = sqq[(size_t)bh * LSEQ + q];
  const float* sqkp = sqk + (size_t)bh * LSEQ;

  // staging: 32 wave-loads of 1KB per tile; wave w does j = w*4 + i (i<4).
  // LDS dest linear (slot j*1024B + lane*16B); global source col
  // pre-swizzled: cs = (ln&7) ^ (rr&7) ^ ((rr>>3)&3).
  const short* sb[4];
  int st[4];
#pragma unroll
  for (int i = 0; i < 4; ++i) {
    int j = w * 4 + i;
    int rr = j * 8 + (ln >> 3);
    int cs = ((ln & 7) ^ (rr & 7) ^ ((rr >> 3) & 3)) * 8;
    if (j < 8)       { sb[i] = Km + bhQ + (size_t)rr * DK + cs;                  st[i] = 64 * DK; }
    else if (j < 16) { sb[i] = Ks + bhQ + (size_t)(rr - 64) * DK + cs;           st[i] = 64 * DK; }
    else if (j < 24) { sb[i] = VmT + ((size_t)bh * DK + (rr - 128)) * LSEQ + cs; st[i] = 64; }
    else             { sb[i] = VsT + ((size_t)bh * DK + (rr - 192)) * LSEQ + cs; st[i] = 64; }
  }

  f32x16 acc[4] = {};
  float prs = 0.f;

  const int krow = ks * 32 + l31;
  const int kswz = ((krow & 7) ^ ((krow >> 3) & 3)) << 4;

  // prolog: issue tile 0 into buf 0
#pragma unroll
  for (int i = 0; i < 4; ++i)
    GLD_LDS(sb[i], poolS + (w * 4 + i) * 512);

  const int NT = LSEQ / 64;
  for (int t = 0; t < NT; ++t) {
    __syncthreads();   // drains vmcnt(0): tile t visible; prev buf reads done
    int cur = (t & 1) * 16384;           // shorts
    // issue loads for tile t+1 into the other buffer (fly during compute)
    if (t + 1 < NT) {
      int nxt = ((t + 1) & 1) * 16384;
#pragma unroll
      for (int i = 0; i < 4; ++i)
        GLD_LDS(sb[i] + (size_t)(t + 1) * st[i], poolS + nxt + (w * 4 + i) * 512);
    }
    const char* base = (const char*)(poolS + cur);

    // QK^T: S[k][q] for this wave's 32-k half, 32 q
    f32x16 sm = {}, ss = {};
#pragma unroll
    for (int d = 0; d < 4; ++d) {
      bf16x8 am = *(const bf16x8*)(base + krow * 128 + ((d * 32 + h * 16) ^ kswz));
      bf16x8 as = *(const bf16x8*)(base + 8192 + krow * 128 + ((d * 32 + h * 16) ^ kswz));
      sm = MFMA32(am, qmf[d], sm);
      ss = MFMA32(as, qsf[d], ss);
    }

    // softmax numerator; S row k_local = (reg&3) + 8*(reg>>2) + 4*h
    float pv[16];
    int k0b = t * 64 + ks * 32;
#pragma unroll
    for (int rq = 0; rq < 4; ++rq) {
      f32x4 rsk = *(const f32x4*)&sqkp[k0b + 8 * rq + 4 * h];
#pragma unroll
      for (int r = 0; r < 4; ++r) {
        int i = rq * 4 + r;
        float w2 = fmaf(-2.f, sm[i] + ss[i], sqQ + rsk[r]);
        float wd = __builtin_amdgcn_sqrtf(fmaxf(w2, 0.f));
        float sim = __expf(-wd);
        float p = __expf(sim);
        prs += p;
        pv[i] = p;
      }
    }
    // pack to bf16 + lane-half swap -> PV B-frags
    unsigned u0 = pk2c(pv[0], pv[1]),   u1 = pk2c(pv[2], pv[3]);
    unsigned u2 = pk2c(pv[4], pv[5]),   u3 = pk2c(pv[6], pv[7]);
    unsigned u4 = pk2c(pv[8], pv[9]),   u5 = pk2c(pv[10], pv[11]);
    unsigned u6 = pk2c(pv[12], pv[13]), u7 = pk2c(pv[14], pv[15]);
    asm volatile("v_permlane32_swap_b32 %0, %1" : "+v"(u0), "+v"(u2));
    asm volatile("v_permlane32_swap_b32 %0, %1" : "+v"(u1), "+v"(u3));
    asm volatile("v_permlane32_swap_b32 %0, %1" : "+v"(u4), "+v"(u6));
    asm volatile("v_permlane32_swap_b32 %0, %1" : "+v"(u5), "+v"(u7));
    union { uint4 u; bf16x8 v; } f0, f1;
    f0.u.x = u0; f0.u.y = u1; f0.u.z = u2; f0.u.w = u3;
    f1.u.x = u4; f1.u.y = u5; f1.u.z = u6; f1.u.w = u7;

    // PV: acc[vblk] += V-frag(32v x 16k) x P-frag
#pragma unroll
    for (int vblk = 0; vblk < 4; ++vblk) {
      int vrow = vblk * 32 + l31;
      int vswz = ((vrow & 7) ^ ((vrow >> 3) & 3)) << 4;
      const char* vbase = base + 16384 + vrow * 128;
      bf16x8 v0 = *(const bf16x8*)(vbase + ((ks * 64 + h * 16) ^ vswz));
      bf16x8 v1 = *(const bf16x8*)(vbase + ((ks * 64 + 32 + h * 16) ^ vswz));
      acc[vblk] = MFMA32(v0, f0.v, acc[vblk]);
      acc[vblk] = MFMA32(v1, f1.v, acc[vblk]);
    }
  }

  // row-sum: reduce over lane halves (k-coverage split by h)
  prs += __shfl_xor(prs, 32);

  // combine k-halves (ks=1 -> ks=0) through LDS scratch
  float* scr  = (float*)pool;             // [4 qg][4 vblk][4 rq][64 ln] f32x4 = 64 KB
  float* scrP = (float*)(pool + 65536);   // [4 qg][64 ln] f32 = 1 KB
  __syncthreads();
  if (ks == 1) {
#pragma unroll
    for (int vblk = 0; vblk < 4; ++vblk)
#pragma unroll
      for (int rq = 0; rq < 4; ++rq) {
        f32x4 qd;
        qd[0] = acc[vblk][rq * 4 + 0]; qd[1] = acc[vblk][rq * 4 + 1];
        qd[2] = acc[vblk][rq * 4 + 2]; qd[3] = acc[vblk][rq * 4 + 3];
        *(f32x4*)&scr[(((qg * 4 + vblk) * 4 + rq) * 64 + ln) * 4] = qd;
      }
    scrP[qg * 64 + ln] = prs;
  }
  __syncthreads();
  if (ks == 0) {
    float inv = 1.f / (prs + scrP[qg * 64 + ln]);
    int b = bh >> 4, hh = bh & 15;
    size_t orow = ((size_t)(b * LSEQ + q)) * DMODEL + hh * DK;
#pragma unroll
    for (int vblk = 0; vblk < 4; ++vblk) {
      short* obuf = (vblk < 2) ? Om : Os;
      int vbase = (vblk & 1) * 32 + 4 * h;
#pragma unroll
      for (int rq = 0; rq < 4; ++rq) {
        f32x4 od = *(const f32x4*)&scr[(((qg * 4 + vblk) * 4 + rq) * 64 + ln) * 4];
        float o0 = (acc[vblk][rq * 4 + 0] + od[0]) * inv;
        float o1 = (acc[vblk][rq * 4 + 1] + od[1]) * inv;
        float o2 = (acc[vblk][rq * 4 + 2] + od[2]) * inv;
        float o3 = (acc[vblk][rq * 4 + 3] + od[3]) * inv;
        uint2 pk; pk.x = pk2c(o0, o1); pk.y = pk2c(o2, o3);
        *(uint2*)(obuf + orow + vbase + 8 * rq) = pk;
      }
    }
  }
}

extern "C" void kernel_launch(void* const* d_in, const int* in_sizes, int n_in,
                              void* d_out, int out_size, void* d_ws, size_t ws_size,
                              hipStream_t stream) {
  const float* mu    = (const float*)d_in[0];
  const float* sigma = (const float*)d_in[1];
  const float* Wqm   = (const float*)d_in[2];
  const float* bqm   = (const float*)d_in[3];
  const float* Wqs   = (const float*)d_in[4];
  const float* bqs   = (const float*)d_in[5];
  const float* Wo    = (const float*)d_in[6];
  const float* bo    = (const float*)d_in[7];
  float* out = (float*)d_out;
  char* ws = (char*)d_ws;
  const size_t MB = 1u << 20;

  short* Amu   = (short*)(ws + 0);        // 8MB, reused as Om
  short* Asg   = (short*)(ws + 8 * MB);   // 8MB, reused as Os (contiguous with Om)
  short* Wqm_t = (short*)(ws + 16 * MB);  // 6MB
  short* Wqs_t = (short*)(ws + 22 * MB);  // 6MB
  short* Wo_t  = (short*)(ws + 28 * MB);  // 2MB
  short* Qm    = (short*)(ws + 30 * MB);  // 8MB each below
  short* Km    = (short*)(ws + 38 * MB);
  short* VmT   = (short*)(ws + 46 * MB);
  short* Qs    = (short*)(ws + 54 * MB);
  short* Ks    = (short*)(ws + 62 * MB);
  short* VsT   = (short*)(ws + 70 * MB);
  float* sqq   = (float*)(ws + 78 * MB);            // 256KB
  float* sqk   = (float*)(ws + 78 * MB + 256 * 1024);
  short* Om = Amu;
  short* Os = Asg;

  cvt_bf16_k<<<2048, 256, 0, stream>>>(mu, Amu, MTOT * DMODEL / 8);
  cvt_bf16_k<<<2048, 256, 0, stream>>>(sigma, Asg, MTOT * DMODEL / 8);
  cvt_tr_k<<<dim3(96, 32), 256, 0, stream>>>(Wqm, Wqm_t, 1024, 3072);
  cvt_tr_k<<<dim3(96, 32), 256, 0, stream>>>(Wqs, Wqs_t, 1024, 3072);
  cvt_tr_k<<<dim3(32, 32), 256, 0, stream>>>(Wo, Wo_t, 1024, 1024);

  gemm128_k<<<dim3(32, 24), 256, 0, stream>>>(Amu, Wqm_t, bqm, 0, nullptr, Qm, Km, VmT);
  gemm128_k<<<dim3(32, 24), 256, 0, stream>>>(Asg, Wqs_t, bqs, 0, nullptr, Qs, Ks, VsT);

  norms_k<<<512, 256, 0, stream>>>(Qm, Qs, Km, Ks, sqq, sqk);

  attn_k<<<dim3(LSEQ / 128, BH), 512, 0, stream>>>(Qm, Km, VmT, Qs, Ks, VsT, sqq, sqk, Om, Os);

  // out-proj for mu and sigma as ONE GEMM (Om|Os contiguous, M=8192)
  gemm128_k<<<dim3(64, 8), 256, 0, stream>>>(Om, Wo_t, bo, 1, out, nullptr, nullptr, nullptr);
}

// Round 11
// 281.620 us; speedup vs baseline: 2.0875x; 1.0098x over previous
//
#include <hip/hip_runtime.h>
#include <hip/hip_bf16.h>

#define LSEQ   2048
#define DK     64
#define NH     16
#define BS     2
#define DMODEL 1024
#define BH     (BS*NH)    // 32
#define MTOT   (BS*LSEQ)  // 4096

typedef __attribute__((ext_vector_type(8))) short bf16x8;
typedef __attribute__((ext_vector_type(4))) float f32x4;
typedef __attribute__((ext_vector_type(16))) float f32x16;

#define MFMA16(a,b,c) __builtin_amdgcn_mfma_f32_16x16x32_bf16((a),(b),(c),0,0,0)
#define MFMA32(a,b,c) __builtin_amdgcn_mfma_f32_32x32x16_bf16((a),(b),(c),0,0,0)
#define GLD_LDS(g,l) __builtin_amdgcn_global_load_lds((const __attribute__((address_space(1))) void*)(g), (__attribute__((address_space(3))) void*)(l), 16, 0, 0)

#define L2E   1.4426950408889634f      // log2(e)
#define L2E2  2.0813689810056077f      // log2(e)^2

__device__ __forceinline__ short f2bs(float f) {
  union { __hip_bfloat16 h; short s; } u; u.h = __float2bfloat16(f); return u.s;
}
__device__ __forceinline__ float b2f(unsigned short s) {
  union { unsigned u; float f; } v; v.u = ((unsigned)s) << 16; return v.f;
}
// cheap round-half-up bf16 (inputs guaranteed finite)
__device__ __forceinline__ unsigned short f2bs_c(float f) {
  union { float f; unsigned u; } v; v.f = f;
  return (unsigned short)((v.u + 0x8000u) >> 16);
}
__device__ __forceinline__ unsigned pk2c(float lo, float hi) {
  union { float f; unsigned u; } a, b; a.f = lo; b.f = hi;
  return ((a.u + 0x8000u) >> 16) | ((b.u + 0x8000u) & 0xffff0000u);
}
__device__ __forceinline__ unsigned pk2(float lo, float hi) {
  return (unsigned)(unsigned short)f2bs(lo) | (((unsigned)(unsigned short)f2bs(hi)) << 16);
}
// raw v_exp_f32 (2^x); VALU->VALU deps are HW-interlocked on CDNA
__device__ __forceinline__ float fexp2(float x) {
  float r; asm("v_exp_f32 %0, %1" : "=v"(r) : "v"(x)); return r;
}
__device__ __forceinline__ float fexp2n(float x) {   // 2^(-x), free input modifier
  float r; asm("v_exp_f32 %0, -%1" : "=v"(r) : "v"(x)); return r;
}

// ---------------- f32 -> bf16 flat convert (vectorized) ----------------
__global__ __launch_bounds__(256) void cvt_bf16_k(const float* __restrict__ in,
                                                  short* __restrict__ out, int n8) {
  for (int i = blockIdx.x * blockDim.x + threadIdx.x; i < n8; i += gridDim.x * blockDim.x) {
    const float4* p = (const float4*)in + (size_t)i * 2;
    float4 a = p[0], b = p[1];
    uint4 o;
    o.x = pk2(a.x, a.y); o.y = pk2(a.z, a.w);
    o.z = pk2(b.x, b.y); o.w = pk2(b.z, b.w);
    ((uint4*)out)[i] = o;
  }
}

// ---------------- f32 [K][N] -> bf16 transposed [N][K] ----------------
__global__ __launch_bounds__(256) void cvt_tr_k(const float* __restrict__ W,
                                                short* __restrict__ Wt,
                                                int Krows, int Ncols) {
  __shared__ float tile[32][33];
  int n0 = blockIdx.x * 32, k0 = blockIdx.y * 32;
  int t = threadIdx.x;
#pragma unroll
  for (int i = 0; i < 4; ++i) {
    int idx = t + i * 256; int r = idx >> 5, c = idx & 31;
    tile[r][c] = W[(size_t)(k0 + r) * Ncols + n0 + c];
  }
  __syncthreads();
#pragma unroll
  for (int i = 0; i < 4; ++i) {
    int idx = t + i * 256; int r = idx >> 5, c = idx & 31;
    Wt[(size_t)(n0 + r) * Krows + k0 + c] = f2bs(tile[c][r]);
  }
}

// ---------------- 128x128-tile bf16 GEMM, K=1024 ----------------
__global__ __launch_bounds__(256) void gemm128_k(
    const short* __restrict__ A, const short* __restrict__ Bt,
    const float* __restrict__ bias, int mode,
    float* __restrict__ outF,
    short* __restrict__ Qb, short* __restrict__ Kb, short* __restrict__ VTb) {
  __shared__ short As[128 * 64];
  __shared__ short Bs[128 * 64];
  int tid = threadIdx.x, w = tid >> 6, ln = tid & 63, lg = ln >> 4, lr = ln & 15;
  int m0 = blockIdx.x * 128, n0 = blockIdx.y * 128;
  int wr = w >> 1, wc = w & 1;
  f32x4 acc[4][4] = {};

  for (int k0 = 0; k0 < 1024; k0 += 64) {
    __syncthreads();
#pragma unroll
    for (int i = 0; i < 4; ++i) {
      int cb = w * 64 + i * 256;
      int c = cb + ln;
      GLD_LDS(A  + (size_t)(m0 + (c >> 3)) * 1024 + k0 + (c & 7) * 8, &As[cb * 8]);
      GLD_LDS(Bt + (size_t)(n0 + (c >> 3)) * 1024 + k0 + (c & 7) * 8, &Bs[cb * 8]);
    }
    __syncthreads();
#pragma unroll
    for (int kh = 0; kh < 2; ++kh) {
      bf16x8 af[4], bfr[4];
#pragma unroll
      for (int mi = 0; mi < 4; ++mi)
        af[mi] = *(const bf16x8*)&As[(wr * 64 + mi * 16 + lr) * 64 + kh * 32 + lg * 8];
#pragma unroll
      for (int ni = 0; ni < 4; ++ni)
        bfr[ni] = *(const bf16x8*)&Bs[(wc * 64 + ni * 16 + lr) * 64 + kh * 32 + lg * 8];
#pragma unroll
      for (int mi = 0; mi < 4; ++mi)
#pragma unroll
        for (int ni = 0; ni < 4; ++ni)
          acc[mi][ni] = MFMA16(af[mi], bfr[ni], acc[mi][ni]);
    }
  }

#pragma unroll
  for (int ni = 0; ni < 4; ++ni) {
    int n = n0 + wc * 64 + ni * 16 + lr;
    float bv = bias[n];
    int part = n >> 10, cc = n & 1023, h = cc >> 6, dd = cc & 63;
#pragma unroll
    for (int mi = 0; mi < 4; ++mi) {
      int mbase = m0 + wr * 64 + mi * 16 + 4 * lg;
      float vv[4];
#pragma unroll
      for (int r = 0; r < 4; ++r) vv[r] = acc[mi][ni][r] + bv;
      if (mode == 1) {
#pragma unroll
        for (int r = 0; r < 4; ++r) outF[(size_t)(mbase + r) * 1024 + n] = vv[r];
      } else if (part == 2) {
        int b = mbase >> 11, tok = mbase & 2047, bh = b * NH + h;
        uint2 pk; pk.x = pk2c(vv[0], vv[1]); pk.y = pk2c(vv[2], vv[3]);
        *(uint2*)&VTb[((size_t)bh * DK + dd) * LSEQ + tok] = pk;
      } else {
        short* dst = (part == 0) ? Qb : Kb;
#pragma unroll
        for (int r = 0; r < 4; ++r) {
          int m = mbase + r;
          int b = m >> 11, tok = m & 2047, bh = b * NH + h;
          dst[((size_t)bh * LSEQ + tok) * DK + dd] = (short)f2bs_c(vv[r]);
        }
      }
    }
  }
}

// ---------------- per-row squared norms (pre-scaled by log2(e)^2) ----------------
__global__ __launch_bounds__(256) void norms_k(
    const short* __restrict__ Qm, const short* __restrict__ Qs,
    const short* __restrict__ Km, const short* __restrict__ Ks,
    float* __restrict__ sqq, float* __restrict__ sqk) {
  int id = blockIdx.x * 256 + threadIdx.x;  // 0..131071
  int row = id & 65535;
  const short* p1 = (id < 65536) ? Qm : Km;
  const short* p2 = (id < 65536) ? Qs : Ks;
  float* outp = (id < 65536) ? sqq : sqk;
  const uint4* a = (const uint4*)(p1 + (size_t)row * DK);
  const uint4* b = (const uint4*)(p2 + (size_t)row * DK);
  float s = 0.f;
#pragma unroll
  for (int i = 0; i < 8; ++i) {
    uint4 x = a[i], y = b[i];
    unsigned vx[4] = {x.x, x.y, x.z, x.w};
    unsigned vy[4] = {y.x, y.y, y.z, y.w};
#pragma unroll
    for (int j = 0; j < 4; ++j) {
      float l1 = b2f((unsigned short)(vx[j] & 0xffff)), h1 = b2f((unsigned short)(vx[j] >> 16));
      float l2 = b2f((unsigned short)(vy[j] & 0xffff)), h2 = b2f((unsigned short)(vy[j] >> 16));
      s += l1 * l1 + h1 * h1 + l2 * l2 + h2 * h2;
    }
  }
  outp[row] = s * L2E2;   // exp2-domain: sqrt((sq_q+sq_k-2S)*L2E2) = L2E*wd
}

// ---------------- fused Wasserstein attention (32x32 MFMA, dbuf, 8 waves) ----------------
// grid (L/128, BH); 512 threads = 8 waves = (qg = w&3) x (ks = w>>2).
// Pool EXACTLY 64 KB: >64KB per block halves residency to 1 block/CU
// (R10 evidence: 66560B -> Occupancy 21.9% ~ 1 block). At 65536B:
// 2 blocks/CU x 8 waves = 4 waves/SIMD, barrier-independent blocks
// fill each other's drain/chain stalls.
// exp2-domain: sqq/sqk pre-scaled by L2E2, fmaf const -2*L2E2 ->
// sqrt gives L2E*wd -> first exp is a raw v_exp with free negate.
// __launch_bounds__ 2nd arg = min BLOCKS/CU (CUDA semantics).
__global__ __launch_bounds__(512, 2) void attn_k(
    const short* __restrict__ Qm, const short* __restrict__ Km, const short* __restrict__ VmT,
    const short* __restrict__ Qs, const short* __restrict__ Ks, const short* __restrict__ VsT,
    const float* __restrict__ sqq, const float* __restrict__ sqk,
    short* __restrict__ Om, short* __restrict__ Os) {
  int bh = blockIdx.y;
  int q0 = blockIdx.x * 128;
  int tid = threadIdx.x, w = tid >> 6, ln = tid & 63;
  int l31 = ln & 31, h = ln >> 5;
  int qg = w & 3, ks = w >> 2;

  // buf layout (per 32KB half): [0,8K) Km [64 rows][64 sh] | [8K,16K) Ks
  // | [16K,32K) Vt [128 rows][64 sh]. Epilogue reuses [0,32K)+[32K,+512).
  __shared__ __align__(16) char pool[65536];
  short* poolS = (short*)pool;

  const size_t bhQ = (size_t)bh * LSEQ * DK;

  // Q fragments (B operand: col = q = l31, k-dim d = dblk*16 + h*8 + j)
  int q = q0 + qg * 32 + l31;
  bf16x8 qmf[4], qsf[4];
#pragma unroll
  for (int d = 0; d < 4; ++d) {
    qmf[d] = *(const bf16x8*)(Qm + bhQ + (size_t)q * DK + d * 16 + h * 8);
    qsf[d] = *(const bf16x8*)(Qs + bhQ + (size_t)q * DK + d * 16 + h * 8);
  }
  float sqQ = sqq[(size_t)bh * LSEQ + q];
  const float* sqkp = sqk + (size_t)bh * LSEQ;

  // staging: 32 wave-loads of 1KB per tile; wave w does j = w*4 + i (i<4).
  // LDS dest linear (slot j*1024B + lane*16B); global source col
  // pre-swizzled: cs = (ln&7) ^ (rr&7) ^ ((rr>>3)&3).
  const short* sb[4];
  int st[4];
#pragma unroll
  for (int i = 0; i < 4; ++i) {
    int j = w * 4 + i;
    int rr = j * 8 + (ln >> 3);
    int cs = ((ln & 7) ^ (rr & 7) ^ ((rr >> 3) & 3)) * 8;
    if (j < 8)       { sb[i] = Km + bhQ + (size_t)rr * DK + cs;                  st[i] = 64 * DK; }
    else if (j < 16) { sb[i] = Ks + bhQ + (size_t)(rr - 64) * DK + cs;           st[i] = 64 * DK; }
    else if (j < 24) { sb[i] = VmT + ((size_t)bh * DK + (rr - 128)) * LSEQ + cs; st[i] = 64; }
    else             { sb[i] = VsT + ((size_t)bh * DK + (rr - 192)) * LSEQ + cs; st[i] = 64; }
  }

  f32x16 acc[4] = {};
  float prs = 0.f;

  const int krow = ks * 32 + l31;
  const int kswz = ((krow & 7) ^ ((krow >> 3) & 3)) << 4;

  // prolog: issue tile 0 into buf 0
#pragma unroll
  for (int i = 0; i < 4; ++i)
    GLD_LDS(sb[i], poolS + (w * 4 + i) * 512);

  const int NT = LSEQ / 64;
  for (int t = 0; t < NT; ++t) {
    __syncthreads();   // drains vmcnt(0): tile t visible; prev buf reads done
    int cur = (t & 1) * 16384;           // shorts
    // issue loads for tile t+1 into the other buffer (fly during compute)
    if (t + 1 < NT) {
      int nxt = ((t + 1) & 1) * 16384;
#pragma unroll
      for (int i = 0; i < 4; ++i)
        GLD_LDS(sb[i] + (size_t)(t + 1) * st[i], poolS + nxt + (w * 4 + i) * 512);
    }
    const char* base = (const char*)(poolS + cur);

    // QK^T: S[k][q] for this wave's 32-k half, 32 q
    f32x16 sm = {}, ss = {};
#pragma unroll
    for (int d = 0; d < 4; ++d) {
      bf16x8 am = *(const bf16x8*)(base + krow * 128 + ((d * 32 + h * 16) ^ kswz));
      bf16x8 as = *(const bf16x8*)(base + 8192 + krow * 128 + ((d * 32 + h * 16) ^ kswz));
      sm = MFMA32(am, qmf[d], sm);
      ss = MFMA32(as, qsf[d], ss);
    }

    // softmax numerator (exp2-domain); S row k_local = (reg&3)+8*(reg>>2)+4*h
    float pv[16];
    int k0b = t * 64 + ks * 32;
#pragma unroll
    for (int rq = 0; rq < 4; ++rq) {
      f32x4 rsk = *(const f32x4*)&sqkp[k0b + 8 * rq + 4 * h];
#pragma unroll
      for (int r = 0; r < 4; ++r) {
        int i = rq * 4 + r;
        float w2 = fmaf(-2.f * L2E2, sm[i] + ss[i], sqQ + rsk[r]);  // = L2E2*wd^2
        float wdp = __builtin_amdgcn_sqrtf(fmaxf(w2, 0.f));         // = L2E*wd
        float sim = fexp2n(wdp);                                    // = exp(-wd)
        float p = fexp2(sim * L2E);                                 // = exp(sim)
        prs += p;
        pv[i] = p;
      }
    }
    // pack to bf16 + lane-half swap -> PV B-frags
    unsigned u0 = pk2c(pv[0], pv[1]),   u1 = pk2c(pv[2], pv[3]);
    unsigned u2 = pk2c(pv[4], pv[5]),   u3 = pk2c(pv[6], pv[7]);
    unsigned u4 = pk2c(pv[8], pv[9]),   u5 = pk2c(pv[10], pv[11]);
    unsigned u6 = pk2c(pv[12], pv[13]), u7 = pk2c(pv[14], pv[15]);
    asm volatile("v_permlane32_swap_b32 %0, %1" : "+v"(u0), "+v"(u2));
    asm volatile("v_permlane32_swap_b32 %0, %1" : "+v"(u1), "+v"(u3));
    asm volatile("v_permlane32_swap_b32 %0, %1" : "+v"(u4), "+v"(u6));
    asm volatile("v_permlane32_swap_b32 %0, %1" : "+v"(u5), "+v"(u7));
    union { uint4 u; bf16x8 v; } f0, f1;
    f0.u.x = u0; f0.u.y = u1; f0.u.z = u2; f0.u.w = u3;
    f1.u.x = u4; f1.u.y = u5; f1.u.z = u6; f1.u.w = u7;

    // PV: acc[vblk] += V-frag(32v x 16k) x P-frag
#pragma unroll
    for (int vblk = 0; vblk < 4; ++vblk) {
      int vrow = vblk * 32 + l31;
      int vswz = ((vrow & 7) ^ ((vrow >> 3) & 3)) << 4;
      const char* vbase = base + 16384 + vrow * 128;
      bf16x8 v0 = *(const bf16x8*)(vbase + ((ks * 64 + h * 16) ^ vswz));
      bf16x8 v1 = *(const bf16x8*)(vbase + ((ks * 64 + 32 + h * 16) ^ vswz));
      acc[vblk] = MFMA32(v0, f0.v, acc[vblk]);
      acc[vblk] = MFMA32(v1, f1.v, acc[vblk]);
    }
  }

  // row-sum: reduce over lane halves (k-coverage split by h)
  prs += __shfl_xor(prs, 32);

  // combine k-halves (ks=1 -> ks=0) in TWO passes of 2 qg-groups each,
  // so scratch (32KB + 512B) fits inside the 64KB pool.
  float* scr  = (float*)pool;             // [2 qgl][4 vblk][4 rq][64 ln] f32x4 = 32 KB
  float* scrP = (float*)(pool + 32768);   // [2 qgl][64 ln] f32 = 512 B
  int b = bh >> 4, hh = bh & 15;
  int qgl = qg & 1;
#pragma unroll
  for (int p = 0; p < 2; ++p) {
    __syncthreads();
    if (ks == 1 && (qg >> 1) == p) {
#pragma unroll
      for (int vblk = 0; vblk < 4; ++vblk)
#pragma unroll
        for (int rq = 0; rq < 4; ++rq) {
          f32x4 qd;
          qd[0] = acc[vblk][rq * 4 + 0]; qd[1] = acc[vblk][rq * 4 + 1];
          qd[2] = acc[vblk][rq * 4 + 2]; qd[3] = acc[vblk][rq * 4 + 3];
          *(f32x4*)&scr[(((qgl * 4 + vblk) * 4 + rq) * 64 + ln) * 4] = qd;
        }
      scrP[qgl * 64 + ln] = prs;
    }
    __syncthreads();
    if (ks == 0 && (qg >> 1) == p) {
      float inv = 1.f / (prs + scrP[qgl * 64 + ln]);
      size_t orow = ((size_t)(b * LSEQ + q)) * DMODEL + hh * DK;
#pragma unroll
      for (int vblk = 0; vblk < 4; ++vblk) {
        short* obuf = (vblk < 2) ? Om : Os;
        int vbase = (vblk & 1) * 32 + 4 * h;
#pragma unroll
        for (int rq = 0; rq < 4; ++rq) {
          f32x4 od = *(const f32x4*)&scr[(((qgl * 4 + vblk) * 4 + rq) * 64 + ln) * 4];
          float o0 = (acc[vblk][rq * 4 + 0] + od[0]) * inv;
          float o1 = (acc[vblk][rq * 4 + 1] + od[1]) * inv;
          float o2 = (acc[vblk][rq * 4 + 2] + od[2]) * inv;
          float o3 = (acc[vblk][rq * 4 + 3] + od[3]) * inv;
          uint2 pk; pk.x = pk2c(o0, o1); pk.y = pk2c(o2, o3);
          *(uint2*)(obuf + orow + vbase + 8 * rq) = pk;
        }
      }
    }
  }
}

extern "C" void kernel_launch(void* const* d_in, const int* in_sizes, int n_in,
                              void* d_out, int out_size, void* d_ws, size_t ws_size,
                              hipStream_t stream) {
  const float* mu    = (const float*)d_in[0];
  const float* sigma = (const float*)d_in[1];
  const float* Wqm   = (const float*)d_in[2];
  const float* bqm   = (const float*)d_in[3];
  const float* Wqs   = (const float*)d_in[4];
  const float* bqs   = (const float*)d_in[5];
  const float* Wo    = (const float*)d_in[6];
  const float* bo    = (const float*)d_in[7];
  float* out = (float*)d_out;
  char* ws = (char*)d_ws;
  const size_t MB = 1u << 20;

  short* Amu   = (short*)(ws + 0);        // 8MB, reused as Om
  short* Asg   = (short*)(ws + 8 * MB);   // 8MB, reused as Os (contiguous with Om)
  short* Wqm_t = (short*)(ws + 16 * MB);  // 6MB
  short* Wqs_t = (short*)(ws + 22 * MB);  // 6MB
  short* Wo_t  = (short*)(ws + 28 * MB);  // 2MB
  short* Qm    = (short*)(ws + 30 * MB);  // 8MB each below
  short* Km    = (short*)(ws + 38 * MB);
  short* VmT   = (short*)(ws + 46 * MB);
  short* Qs    = (short*)(ws + 54 * MB);
  short* Ks    = (short*)(ws + 62 * MB);
  short* VsT   = (short*)(ws + 70 * MB);
  float* sqq   = (float*)(ws + 78 * MB);            // 256KB
  float* sqk   = (float*)(ws + 78 * MB + 256 * 1024);
  short* Om = Amu;
  short* Os = Asg;

  cvt_bf16_k<<<2048, 256, 0, stream>>>(mu, Amu, MTOT * DMODEL / 8);
  cvt_bf16_k<<<2048, 256, 0, stream>>>(sigma, Asg, MTOT * DMODEL / 8);
  cvt_tr_k<<<dim3(96, 32), 256, 0, stream>>>(Wqm, Wqm_t, 1024, 3072);
  cvt_tr_k<<<dim3(96, 32), 256, 0, stream>>>(Wqs, Wqs_t, 1024, 3072);
  cvt_tr_k<<<dim3(32, 32), 256, 0, stream>>>(Wo, Wo_t, 1024, 1024);

  gemm128_k<<<dim3(32, 24), 256, 0, stream>>>(Amu, Wqm_t, bqm, 0, nullptr, Qm, Km, VmT);
  gemm128_k<<<dim3(32, 24), 256, 0, stream>>>(Asg, Wqs_t, bqs, 0, nullptr, Qs, Ks, VsT);

  norms_k<<<512, 256, 0, stream>>>(Qm, Qs, Km, Ks, sqq, sqk);

  attn_k<<<dim3(LSEQ / 128, BH), 512, 0, stream>>>(Qm, Km, VmT, Qs, Ks, VsT, sqq, sqk, Om, Os);

  // out-proj for mu and sigma as ONE GEMM (Om|Os contiguous, M=8192)
  gemm128_k<<<dim3(64, 8), 256, 0, stream>>>(Om, Wo_t, bo, 1, out, nullptr, nullptr, nullptr);
}

// Round 12
// 277.828 us; speedup vs baseline: 2.1160x; 1.0136x over previous
//
#include <hip/hip_runtime.h>
#include <hip/hip_bf16.h>

#define LSEQ   2048
#define DK     64
#define NH     16
#define BS     2
#define DMODEL 1024
#define BH     (BS*NH)    // 32
#define MTOT   (BS*LSEQ)  // 4096

typedef __attribute__((ext_vector_type(8))) short bf16x8;
typedef __attribute__((ext_vector_type(4))) float f32x4;
typedef __attribute__((ext_vector_type(16))) float f32x16;

#define MFMA16(a,b,c) __builtin_amdgcn_mfma_f32_16x16x32_bf16((a),(b),(c),0,0,0)
#define MFMA32(a,b,c) __builtin_amdgcn_mfma_f32_32x32x16_bf16((a),(b),(c),0,0,0)
#define GLD_LDS(g,l) __builtin_amdgcn_global_load_lds((const __attribute__((address_space(1))) void*)(g), (__attribute__((address_space(3))) void*)(l), 16, 0, 0)

#define L2E   1.4426950408889634f      // log2(e)
#define L2E2  2.0813689810056077f      // log2(e)^2

__device__ __forceinline__ short f2bs(float f) {
  union { __hip_bfloat16 h; short s; } u; u.h = __float2bfloat16(f); return u.s;
}
__device__ __forceinline__ float b2f(unsigned short s) {
  union { unsigned u; float f; } v; v.u = ((unsigned)s) << 16; return v.f;
}
// cheap round-half-up bf16 (inputs guaranteed finite)
__device__ __forceinline__ unsigned short f2bs_c(float f) {
  union { float f; unsigned u; } v; v.f = f;
  return (unsigned short)((v.u + 0x8000u) >> 16);
}
__device__ __forceinline__ unsigned pk2c(float lo, float hi) {
  union { float f; unsigned u; } a, b; a.f = lo; b.f = hi;
  return ((a.u + 0x8000u) >> 16) | ((b.u + 0x8000u) & 0xffff0000u);
}
__device__ __forceinline__ unsigned pk2(float lo, float hi) {
  return (unsigned)(unsigned short)f2bs(lo) | (((unsigned)(unsigned short)f2bs(hi)) << 16);
}
// raw v_exp_f32 (2^x); VALU->VALU deps are HW-interlocked on CDNA
__device__ __forceinline__ float fexp2(float x) {
  float r; asm("v_exp_f32 %0, %1" : "=v"(r) : "v"(x)); return r;
}
__device__ __forceinline__ float fexp2n(float x) {   // 2^(-x), free input modifier
  float r; asm("v_exp_f32 %0, -%1" : "=v"(r) : "v"(x)); return r;
}

// ---------------- f32 -> bf16 flat convert (vectorized) ----------------
__global__ __launch_bounds__(256) void cvt_bf16_k(const float* __restrict__ in,
                                                  short* __restrict__ out, int n8) {
  for (int i = blockIdx.x * blockDim.x + threadIdx.x; i < n8; i += gridDim.x * blockDim.x) {
    const float4* p = (const float4*)in + (size_t)i * 2;
    float4 a = p[0], b = p[1];
    uint4 o;
    o.x = pk2(a.x, a.y); o.y = pk2(a.z, a.w);
    o.z = pk2(b.x, b.y); o.w = pk2(b.z, b.w);
    ((uint4*)out)[i] = o;
  }
}

// ---------------- f32 [K][N] -> bf16 transposed [N][K] ----------------
__global__ __launch_bounds__(256) void cvt_tr_k(const float* __restrict__ W,
                                                short* __restrict__ Wt,
                                                int Krows, int Ncols) {
  __shared__ float tile[32][33];
  int n0 = blockIdx.x * 32, k0 = blockIdx.y * 32;
  int t = threadIdx.x;
#pragma unroll
  for (int i = 0; i < 4; ++i) {
    int idx = t + i * 256; int r = idx >> 5, c = idx & 31;
    tile[r][c] = W[(size_t)(k0 + r) * Ncols + n0 + c];
  }
  __syncthreads();
#pragma unroll
  for (int i = 0; i < 4; ++i) {
    int idx = t + i * 256; int r = idx >> 5, c = idx & 31;
    Wt[(size_t)(n0 + r) * Krows + k0 + c] = f2bs(tile[c][r]);
  }
}

// ---------------- 128x128-tile bf16 GEMM, K=1024 ----------------
__global__ __launch_bounds__(256) void gemm128_k(
    const short* __restrict__ A, const short* __restrict__ Bt,
    const float* __restrict__ bias, int mode,
    float* __restrict__ outF,
    short* __restrict__ Qb, short* __restrict__ Kb, short* __restrict__ VTb) {
  __shared__ short As[128 * 64];
  __shared__ short Bs[128 * 64];
  int tid = threadIdx.x, w = tid >> 6, ln = tid & 63, lg = ln >> 4, lr = ln & 15;
  int m0 = blockIdx.x * 128, n0 = blockIdx.y * 128;
  int wr = w >> 1, wc = w & 1;
  f32x4 acc[4][4] = {};

  for (int k0 = 0; k0 < 1024; k0 += 64) {
    __syncthreads();
#pragma unroll
    for (int i = 0; i < 4; ++i) {
      int cb = w * 64 + i * 256;
      int c = cb + ln;
      GLD_LDS(A  + (size_t)(m0 + (c >> 3)) * 1024 + k0 + (c & 7) * 8, &As[cb * 8]);
      GLD_LDS(Bt + (size_t)(n0 + (c >> 3)) * 1024 + k0 + (c & 7) * 8, &Bs[cb * 8]);
    }
    __syncthreads();
#pragma unroll
    for (int kh = 0; kh < 2; ++kh) {
      bf16x8 af[4], bfr[4];
#pragma unroll
      for (int mi = 0; mi < 4; ++mi)
        af[mi] = *(const bf16x8*)&As[(wr * 64 + mi * 16 + lr) * 64 + kh * 32 + lg * 8];
#pragma unroll
      for (int ni = 0; ni < 4; ++ni)
        bfr[ni] = *(const bf16x8*)&Bs[(wc * 64 + ni * 16 + lr) * 64 + kh * 32 + lg * 8];
#pragma unroll
      for (int mi = 0; mi < 4; ++mi)
#pragma unroll
        for (int ni = 0; ni < 4; ++ni)
          acc[mi][ni] = MFMA16(af[mi], bfr[ni], acc[mi][ni]);
    }
  }

#pragma unroll
  for (int ni = 0; ni < 4; ++ni) {
    int n = n0 + wc * 64 + ni * 16 + lr;
    float bv = bias[n];
    int part = n >> 10, cc = n & 1023, h = cc >> 6, dd = cc & 63;
#pragma unroll
    for (int mi = 0; mi < 4; ++mi) {
      int mbase = m0 + wr * 64 + mi * 16 + 4 * lg;
      float vv[4];
#pragma unroll
      for (int r = 0; r < 4; ++r) vv[r] = acc[mi][ni][r] + bv;
      if (mode == 1) {
#pragma unroll
        for (int r = 0; r < 4; ++r) outF[(size_t)(mbase + r) * 1024 + n] = vv[r];
      } else if (part == 2) {
        int b = mbase >> 11, tok = mbase & 2047, bh = b * NH + h;
        uint2 pk; pk.x = pk2c(vv[0], vv[1]); pk.y = pk2c(vv[2], vv[3]);
        *(uint2*)&VTb[((size_t)bh * DK + dd) * LSEQ + tok] = pk;
      } else {
        short* dst = (part == 0) ? Qb : Kb;
#pragma unroll
        for (int r = 0; r < 4; ++r) {
          int m = mbase + r;
          int b = m >> 11, tok = m & 2047, bh = b * NH + h;
          dst[((size_t)bh * LSEQ + tok) * DK + dd] = (short)f2bs_c(vv[r]);
        }
      }
    }
  }
}

// ---------------- per-row squared norms (pre-scaled by log2(e)^2) ----------------
__global__ __launch_bounds__(256) void norms_k(
    const short* __restrict__ Qm, const short* __restrict__ Qs,
    const short* __restrict__ Km, const short* __restrict__ Ks,
    float* __restrict__ sqq, float* __restrict__ sqk) {
  int id = blockIdx.x * 256 + threadIdx.x;  // 0..131071
  int row = id & 65535;
  const short* p1 = (id < 65536) ? Qm : Km;
  const short* p2 = (id < 65536) ? Qs : Ks;
  float* outp = (id < 65536) ? sqq : sqk;
  const uint4* a = (const uint4*)(p1 + (size_t)row * DK);
  const uint4* b = (const uint4*)(p2 + (size_t)row * DK);
  float s = 0.f;
#pragma unroll
  for (int i = 0; i < 8; ++i) {
    uint4 x = a[i], y = b[i];
    unsigned vx[4] = {x.x, x.y, x.z, x.w};
    unsigned vy[4] = {y.x, y.y, y.z, y.w};
#pragma unroll
    for (int j = 0; j < 4; ++j) {
      float l1 = b2f((unsigned short)(vx[j] & 0xffff)), h1 = b2f((unsigned short)(vx[j] >> 16));
      float l2 = b2f((unsigned short)(vy[j] & 0xffff)), h2 = b2f((unsigned short)(vy[j] >> 16));
      s += l1 * l1 + h1 * h1 + l2 * l2 + h2 * h2;
    }
  }
  outp[row] = s * L2E2;   // exp2-domain: sqrt((sq_q+sq_k-2S)*L2E2) = L2E*wd
}

// ---------------- fused Wasserstein attention (32x32 MFMA, dbuf, 8 waves) ----------------
// grid 512 blocks; XCD-aware remap (T1): flat id -> xcd = id&7 (HW round-
// robin), each XCD owns bh in [xcd*4, xcd*4+4) x 16 q-tiles, so the 16
// q-blocks re-reading one head's 1MB K/V all sit on ONE XCD's L2
// (4 heads x 1MB = 4MB = L2 capacity). Converts K/V re-fetch from HBM
// (~900cy, FETCH 140MB) to L2 hits (~200cy).
// Wave-program unchanged from R8/R11: 0 bank conflicts, dbuf pipelined,
// in-reg P via permlane32_swap, exp2-domain softmax.
__global__ __launch_bounds__(512, 2) void attn_k(
    const short* __restrict__ Qm, const short* __restrict__ Km, const short* __restrict__ VmT,
    const short* __restrict__ Qs, const short* __restrict__ Ks, const short* __restrict__ VsT,
    const float* __restrict__ sqq, const float* __restrict__ sqk,
    short* __restrict__ Om, short* __restrict__ Os) {
  int id = blockIdx.y * 16 + blockIdx.x;   // gridDim = (16, 32)
  int seq = id >> 3;
  int bh = (id & 7) * 4 + (seq >> 4);
  int q0 = (seq & 15) * 128;
  int tid = threadIdx.x, w = tid >> 6, ln = tid & 63;
  int l31 = ln & 31, h = ln >> 5;
  int qg = w & 3, ks = w >> 2;

  // buf layout (per 32KB half): [0,8K) Km [64 rows][64 sh] | [8K,16K) Ks
  // | [16K,32K) Vt [128 rows][64 sh]. Epilogue reuses [0,32K)+[32K,+512).
  __shared__ __align__(16) char pool[65536];
  short* poolS = (short*)pool;

  const size_t bhQ = (size_t)bh * LSEQ * DK;

  // Q fragments (B operand: col = q = l31, k-dim d = dblk*16 + h*8 + j)
  int q = q0 + qg * 32 + l31;
  bf16x8 qmf[4], qsf[4];
#pragma unroll
  for (int d = 0; d < 4; ++d) {
    qmf[d] = *(const bf16x8*)(Qm + bhQ + (size_t)q * DK + d * 16 + h * 8);
    qsf[d] = *(const bf16x8*)(Qs + bhQ + (size_t)q * DK + d * 16 + h * 8);
  }
  float sqQ = sqq[(size_t)bh * LSEQ + q];
  const float* sqkp = sqk + (size_t)bh * LSEQ;

  // staging: 32 wave-loads of 1KB per tile; wave w does j = w*4 + i (i<4).
  // LDS dest linear (slot j*1024B + lane*16B); global source col
  // pre-swizzled: cs = (ln&7) ^ (rr&7) ^ ((rr>>3)&3).
  const short* sb[4];
  int st[4];
#pragma unroll
  for (int i = 0; i < 4; ++i) {
    int j = w * 4 + i;
    int rr = j * 8 + (ln >> 3);
    int cs = ((ln & 7) ^ (rr & 7) ^ ((rr >> 3) & 3)) * 8;
    if (j < 8)       { sb[i] = Km + bhQ + (size_t)rr * DK + cs;                  st[i] = 64 * DK; }
    else if (j < 16) { sb[i] = Ks + bhQ + (size_t)(rr - 64) * DK + cs;           st[i] = 64 * DK; }
    else if (j < 24) { sb[i] = VmT + ((size_t)bh * DK + (rr - 128)) * LSEQ + cs; st[i] = 64; }
    else             { sb[i] = VsT + ((size_t)bh * DK + (rr - 192)) * LSEQ + cs; st[i] = 64; }
  }

  f32x16 acc[4] = {};
  float prs = 0.f;

  const int krow = ks * 32 + l31;
  const int kswz = ((krow & 7) ^ ((krow >> 3) & 3)) << 4;

  // prolog: issue tile 0 into buf 0
#pragma unroll
  for (int i = 0; i < 4; ++i)
    GLD_LDS(sb[i], poolS + (w * 4 + i) * 512);

  const int NT = LSEQ / 64;
  for (int t = 0; t < NT; ++t) {
    __syncthreads();   // drains vmcnt(0): tile t visible; prev buf reads done
    int cur = (t & 1) * 16384;           // shorts
    // issue loads for tile t+1 into the other buffer (fly during compute)
    if (t + 1 < NT) {
      int nxt = ((t + 1) & 1) * 16384;
#pragma unroll
      for (int i = 0; i < 4; ++i)
        GLD_LDS(sb[i] + (size_t)(t + 1) * st[i], poolS + nxt + (w * 4 + i) * 512);
    }
    const char* base = (const char*)(poolS + cur);

    // QK^T: S[k][q] for this wave's 32-k half, 32 q
    f32x16 sm = {}, ss = {};
#pragma unroll
    for (int d = 0; d < 4; ++d) {
      bf16x8 am = *(const bf16x8*)(base + krow * 128 + ((d * 32 + h * 16) ^ kswz));
      bf16x8 as = *(const bf16x8*)(base + 8192 + krow * 128 + ((d * 32 + h * 16) ^ kswz));
      sm = MFMA32(am, qmf[d], sm);
      ss = MFMA32(as, qsf[d], ss);
    }

    // softmax numerator (exp2-domain); S row k_local = (reg&3)+8*(reg>>2)+4*h
    float pv[16];
    int k0b = t * 64 + ks * 32;
#pragma unroll
    for (int rq = 0; rq < 4; ++rq) {
      f32x4 rsk = *(const f32x4*)&sqkp[k0b + 8 * rq + 4 * h];
#pragma unroll
      for (int r = 0; r < 4; ++r) {
        int i = rq * 4 + r;
        float w2 = fmaf(-2.f * L2E2, sm[i] + ss[i], sqQ + rsk[r]);  // = L2E2*wd^2
        float wdp = __builtin_amdgcn_sqrtf(fmaxf(w2, 0.f));         // = L2E*wd
        float sim = fexp2n(wdp);                                    // = exp(-wd)
        float p = fexp2(sim * L2E);                                 // = exp(sim)
        prs += p;
        pv[i] = p;
      }
    }
    // pack to bf16 + lane-half swap -> PV B-frags
    unsigned u0 = pk2c(pv[0], pv[1]),   u1 = pk2c(pv[2], pv[3]);
    unsigned u2 = pk2c(pv[4], pv[5]),   u3 = pk2c(pv[6], pv[7]);
    unsigned u4 = pk2c(pv[8], pv[9]),   u5 = pk2c(pv[10], pv[11]);
    unsigned u6 = pk2c(pv[12], pv[13]), u7 = pk2c(pv[14], pv[15]);
    asm volatile("v_permlane32_swap_b32 %0, %1" : "+v"(u0), "+v"(u2));
    asm volatile("v_permlane32_swap_b32 %0, %1" : "+v"(u1), "+v"(u3));
    asm volatile("v_permlane32_swap_b32 %0, %1" : "+v"(u4), "+v"(u6));
    asm volatile("v_permlane32_swap_b32 %0, %1" : "+v"(u5), "+v"(u7));
    union { uint4 u; bf16x8 v; } f0, f1;
    f0.u.x = u0; f0.u.y = u1; f0.u.z = u2; f0.u.w = u3;
    f1.u.x = u4; f1.u.y = u5; f1.u.z = u6; f1.u.w = u7;

    // PV: acc[vblk] += V-frag(32v x 16k) x P-frag
#pragma unroll
    for (int vblk = 0; vblk < 4; ++vblk) {
      int vrow = vblk * 32 + l31;
      int vswz = ((vrow & 7) ^ ((vrow >> 3) & 3)) << 4;
      const char* vbase = base + 16384 + vrow * 128;
      bf16x8 v0 = *(const bf16x8*)(vbase + ((ks * 64 + h * 16) ^ vswz));
      bf16x8 v1 = *(const bf16x8*)(vbase + ((ks * 64 + 32 + h * 16) ^ vswz));
      acc[vblk] = MFMA32(v0, f0.v, acc[vblk]);
      acc[vblk] = MFMA32(v1, f1.v, acc[vblk]);
    }
  }

  // row-sum: reduce over lane halves (k-coverage split by h)
  prs += __shfl_xor(prs, 32);

  // combine k-halves (ks=1 -> ks=0) in TWO passes of 2 qg-groups each,
  // so scratch (32KB + 512B) fits inside the 64KB pool.
  float* scr  = (float*)pool;             // [2 qgl][4 vblk][4 rq][64 ln] f32x4 = 32 KB
  float* scrP = (float*)(pool + 32768);   // [2 qgl][64 ln] f32 = 512 B
  int b = bh >> 4, hh = bh & 15;
  int qgl = qg & 1;
#pragma unroll
  for (int p = 0; p < 2; ++p) {
    __syncthreads();
    if (ks == 1 && (qg >> 1) == p) {
#pragma unroll
      for (int vblk = 0; vblk < 4; ++vblk)
#pragma unroll
        for (int rq = 0; rq < 4; ++rq) {
          f32x4 qd;
          qd[0] = acc[vblk][rq * 4 + 0]; qd[1] = acc[vblk][rq * 4 + 1];
          qd[2] = acc[vblk][rq * 4 + 2]; qd[3] = acc[vblk][rq * 4 + 3];
          *(f32x4*)&scr[(((qgl * 4 + vblk) * 4 + rq) * 64 + ln) * 4] = qd;
        }
      scrP[qgl * 64 + ln] = prs;
    }
    __syncthreads();
    if (ks == 0 && (qg >> 1) == p) {
      float inv = 1.f / (prs + scrP[qgl * 64 + ln]);
      size_t orow = ((size_t)(b * LSEQ + q)) * DMODEL + hh * DK;
#pragma unroll
      for (int vblk = 0; vblk < 4; ++vblk) {
        short* obuf = (vblk < 2) ? Om : Os;
        int vbase = (vblk & 1) * 32 + 4 * h;
#pragma unroll
        for (int rq = 0; rq < 4; ++rq) {
          f32x4 od = *(const f32x4*)&scr[(((qgl * 4 + vblk) * 4 + rq) * 64 + ln) * 4];
          float o0 = (acc[vblk][rq * 4 + 0] + od[0]) * inv;
          float o1 = (acc[vblk][rq * 4 + 1] + od[1]) * inv;
          float o2 = (acc[vblk][rq * 4 + 2] + od[2]) * inv;
          float o3 = (acc[vblk][rq * 4 + 3] + od[3]) * inv;
          uint2 pk; pk.x = pk2c(o0, o1); pk.y = pk2c(o2, o3);
          *(uint2*)(obuf + orow + vbase + 8 * rq) = pk;
        }
      }
    }
  }
}

extern "C" void kernel_launch(void* const* d_in, const int* in_sizes, int n_in,
                              void* d_out, int out_size, void* d_ws, size_t ws_size,
                              hipStream_t stream) {
  const float* mu    = (const float*)d_in[0];
  const float* sigma = (const float*)d_in[1];
  const float* Wqm   = (const float*)d_in[2];
  const float* bqm   = (const float*)d_in[3];
  const float* Wqs   = (const float*)d_in[4];
  const float* bqs   = (const float*)d_in[5];
  const float* Wo    = (const float*)d_in[6];
  const float* bo    = (const float*)d_in[7];
  float* out = (float*)d_out;
  char* ws = (char*)d_ws;
  const size_t MB = 1u << 20;

  short* Amu   = (short*)(ws + 0);        // 8MB, reused as Om
  short* Asg   = (short*)(ws + 8 * MB);   // 8MB, reused as Os (contiguous with Om)
  short* Wqm_t = (short*)(ws + 16 * MB);  // 6MB
  short* Wqs_t = (short*)(ws + 22 * MB);  // 6MB
  short* Wo_t  = (short*)(ws + 28 * MB);  // 2MB
  short* Qm    = (short*)(ws + 30 * MB);  // 8MB each below
  short* Km    = (short*)(ws + 38 * MB);
  short* VmT   = (short*)(ws + 46 * MB);
  short* Qs    = (short*)(ws + 54 * MB);
  short* Ks    = (short*)(ws + 62 * MB);
  short* VsT   = (short*)(ws + 70 * MB);
  float* sqq   = (float*)(ws + 78 * MB);            // 256KB
  float* sqk   = (float*)(ws + 78 * MB + 256 * 1024);
  short* Om = Amu;
  short* Os = Asg;

  cvt_bf16_k<<<2048, 256, 0, stream>>>(mu, Amu, MTOT * DMODEL / 8);
  cvt_bf16_k<<<2048, 256, 0, stream>>>(sigma, Asg, MTOT * DMODEL / 8);
  cvt_tr_k<<<dim3(96, 32), 256, 0, stream>>>(Wqm, Wqm_t, 1024, 3072);
  cvt_tr_k<<<dim3(96, 32), 256, 0, stream>>>(Wqs, Wqs_t, 1024, 3072);
  cvt_tr_k<<<dim3(32, 32), 256, 0, stream>>>(Wo, Wo_t, 1024, 1024);

  gemm128_k<<<dim3(32, 24), 256, 0, stream>>>(Amu, Wqm_t, bqm, 0, nullptr, Qm, Km, VmT);
  gemm128_k<<<dim3(32, 24), 256, 0, stream>>>(Asg, Wqs_t, bqs, 0, nullptr, Qs, Ks, VsT);

  norms_k<<<512, 256, 0, stream>>>(Qm, Qs, Km, Ks, sqq, sqk);

  attn_k<<<dim3(16, 32), 512, 0, stream>>>(Qm, Km, VmT, Qs, Ks, VsT, sqq, sqk, Om, Os);

  // out-proj for mu and sigma as ONE GEMM (Om|Os contiguous, M=8192)
  gemm128_k<<<dim3(64, 8), 256, 0, stream>>>(Om, Wo_t, bo, 1, out, nullptr, nullptr, nullptr);
}

// Round 13
// 259.357 us; speedup vs baseline: 2.2667x; 1.0712x over previous
//
#include <hip/hip_runtime.h>
#include <hip/hip_bf16.h>

#define LSEQ   2048
#define DK     64
#define NH     16
#define BS     2
#define DMODEL 1024
#define BH     (BS*NH)    // 32
#define MTOT   (BS*LSEQ)  // 4096

typedef __attribute__((ext_vector_type(8))) short bf16x8;
typedef __attribute__((ext_vector_type(4))) float f32x4;
typedef __attribute__((ext_vector_type(16))) float f32x16;

#define MFMA16(a,b,c) __builtin_amdgcn_mfma_f32_16x16x32_bf16((a),(b),(c),0,0,0)
#define MFMA32(a,b,c) __builtin_amdgcn_mfma_f32_32x32x16_bf16((a),(b),(c),0,0,0)
#define GLD_LDS(g,l) __builtin_amdgcn_global_load_lds((const __attribute__((address_space(1))) void*)(g), (__attribute__((address_space(3))) void*)(l), 16, 0, 0)

#define L2E   1.4426950408889634f      // log2(e)
#define L2E2  2.0813689810056077f      // log2(e)^2

__device__ __forceinline__ short f2bs(float f) {
  union { __hip_bfloat16 h; short s; } u; u.h = __float2bfloat16(f); return u.s;
}
__device__ __forceinline__ float b2f(unsigned short s) {
  union { unsigned u; float f; } v; v.u = ((unsigned)s) << 16; return v.f;
}
// cheap round-half-up bf16 (inputs guaranteed finite)
__device__ __forceinline__ unsigned short f2bs_c(float f) {
  union { float f; unsigned u; } v; v.f = f;
  return (unsigned short)((v.u + 0x8000u) >> 16);
}
__device__ __forceinline__ unsigned pk2c(float lo, float hi) {
  union { float f; unsigned u; } a, b; a.f = lo; b.f = hi;
  return ((a.u + 0x8000u) >> 16) | ((b.u + 0x8000u) & 0xffff0000u);
}
__device__ __forceinline__ unsigned pk2(float lo, float hi) {
  return (unsigned)(unsigned short)f2bs(lo) | (((unsigned)(unsigned short)f2bs(hi)) << 16);
}
// raw v_exp_f32 (2^x); VALU->VALU deps are HW-interlocked on CDNA
__device__ __forceinline__ float fexp2(float x) {
  float r; asm("v_exp_f32 %0, %1" : "=v"(r) : "v"(x)); return r;
}
__device__ __forceinline__ float fexp2n(float x) {   // 2^(-x), free input modifier
  float r; asm("v_exp_f32 %0, -%1" : "=v"(r) : "v"(x)); return r;
}

// ---------------- f32 -> bf16 flat convert, mu AND sigma in one launch ----------------
__global__ __launch_bounds__(256) void cvt2_k(const float* __restrict__ a,
                                              const float* __restrict__ b,
                                              short* __restrict__ oa,
                                              short* __restrict__ ob, int n8) {
  int total = n8 * 2;
  for (int i = blockIdx.x * blockDim.x + threadIdx.x; i < total; i += gridDim.x * blockDim.x) {
    int sel = i >= n8;
    int j = sel ? i - n8 : i;
    const float4* p = (const float4*)(sel ? b : a) + (size_t)j * 2;
    float4 x = p[0], y = p[1];
    uint4 o;
    o.x = pk2(x.x, x.y); o.y = pk2(x.z, x.w);
    o.z = pk2(y.x, y.y); o.w = pk2(y.z, y.w);
    ((uint4*)(sel ? ob : oa))[j] = o;
  }
}

// ---------------- all three weight transposes (f32 [K][N] -> bf16 [N][K]) ----------------
__global__ __launch_bounds__(256) void cvt_tr_all_k(
    const float* __restrict__ Wqm, const float* __restrict__ Wqs, const float* __restrict__ Wo,
    short* __restrict__ Wqm_t, short* __restrict__ Wqs_t, short* __restrict__ Wo_t) {
  __shared__ float tile[32][33];
  int id = blockIdx.x;
  const float* W; short* Wt; int Ncols, bx;
  if (id < 3072)      { W = Wqm; Wt = Wqm_t; Ncols = 3072; bx = id % 96; id /= 96; }
  else if (id < 6144) { id -= 3072; W = Wqs; Wt = Wqs_t; Ncols = 3072; bx = id % 96; id /= 96; }
  else                { id -= 6144; W = Wo;  Wt = Wo_t;  Ncols = 1024; bx = id % 32; id /= 32; }
  int n0 = bx * 32, k0 = id * 32;
  int t = threadIdx.x;
#pragma unroll
  for (int i = 0; i < 4; ++i) {
    int idx = t + i * 256; int r = idx >> 5, c = idx & 31;
    tile[r][c] = W[(size_t)(k0 + r) * Ncols + n0 + c];
  }
  __syncthreads();
#pragma unroll
  for (int i = 0; i < 4; ++i) {
    int idx = t + i * 256; int r = idx >> 5, c = idx & 31;
    Wt[(size_t)(n0 + r) * 1024 + k0 + c] = f2bs(tile[c][r]);
  }
}

// ---------------- fused QKV GEMM (mu + sigma in ONE dispatch), 128x128 tile ----------------
__global__ __launch_bounds__(256) void qkv_gemm_k(
    const short* __restrict__ Amu, const short* __restrict__ Asg,
    const short* __restrict__ Wqm_t, const short* __restrict__ Wqs_t,
    const float* __restrict__ bqm, const float* __restrict__ bqs,
    short* __restrict__ Qm, short* __restrict__ Km, short* __restrict__ VmT,
    short* __restrict__ Qs, short* __restrict__ Ks, short* __restrict__ VsT) {
  __shared__ short As[128 * 64];
  __shared__ short Bs[128 * 64];
  int ny = blockIdx.y;                 // 0..47; >=24 -> sigma set
  int sg = ny >= 24;
  int n0 = (sg ? ny - 24 : ny) * 128;
  const short* A  = sg ? Asg : Amu;
  const short* Bt = sg ? Wqs_t : Wqm_t;
  const float* bias = sg ? bqs : bqm;
  short* Qb  = sg ? Qs : Qm;
  short* Kb  = sg ? Ks : Km;
  short* VTb = sg ? VsT : VmT;

  int tid = threadIdx.x, w = tid >> 6, ln = tid & 63, lg = ln >> 4, lr = ln & 15;
  int m0 = blockIdx.x * 128;
  int wr = w >> 1, wc = w & 1;
  f32x4 acc[4][4] = {};

  for (int k0 = 0; k0 < 1024; k0 += 64) {
    __syncthreads();
#pragma unroll
    for (int i = 0; i < 4; ++i) {
      int cb = w * 64 + i * 256;
      int c = cb + ln;
      GLD_LDS(A  + (size_t)(m0 + (c >> 3)) * 1024 + k0 + (c & 7) * 8, &As[cb * 8]);
      GLD_LDS(Bt + (size_t)(n0 + (c >> 3)) * 1024 + k0 + (c & 7) * 8, &Bs[cb * 8]);
    }
    __syncthreads();
#pragma unroll
    for (int kh = 0; kh < 2; ++kh) {
      bf16x8 af[4], bfr[4];
#pragma unroll
      for (int mi = 0; mi < 4; ++mi)
        af[mi] = *(const bf16x8*)&As[(wr * 64 + mi * 16 + lr) * 64 + kh * 32 + lg * 8];
#pragma unroll
      for (int ni = 0; ni < 4; ++ni)
        bfr[ni] = *(const bf16x8*)&Bs[(wc * 64 + ni * 16 + lr) * 64 + kh * 32 + lg * 8];
#pragma unroll
      for (int mi = 0; mi < 4; ++mi)
#pragma unroll
        for (int ni = 0; ni < 4; ++ni)
          acc[mi][ni] = MFMA16(af[mi], bfr[ni], acc[mi][ni]);
    }
  }

#pragma unroll
  for (int ni = 0; ni < 4; ++ni) {
    int n = n0 + wc * 64 + ni * 16 + lr;
    float bv = bias[n];
    int part = n >> 10, cc = n & 1023, hh = cc >> 6, dd = cc & 63;
#pragma unroll
    for (int mi = 0; mi < 4; ++mi) {
      int mbase = m0 + wr * 64 + mi * 16 + 4 * lg;
      float vv[4];
#pragma unroll
      for (int r = 0; r < 4; ++r) vv[r] = acc[mi][ni][r] + bv;
      if (part == 2) {
        int b = mbase >> 11, tok = mbase & 2047, bh = b * NH + hh;
        uint2 pk; pk.x = pk2c(vv[0], vv[1]); pk.y = pk2c(vv[2], vv[3]);
        *(uint2*)&VTb[((size_t)bh * DK + dd) * LSEQ + tok] = pk;
      } else {
        short* dst = (part == 0) ? Qb : Kb;
#pragma unroll
        for (int r = 0; r < 4; ++r) {
          int m = mbase + r;
          int b = m >> 11, tok = m & 2047, bh = b * NH + hh;
          dst[((size_t)bh * LSEQ + tok) * DK + dd] = (short)f2bs_c(vv[r]);
        }
      }
    }
  }
}

// ---------------- 128x128-tile bf16 GEMM (out-proj, f32 out) ----------------
__global__ __launch_bounds__(256) void gemm128_k(
    const short* __restrict__ A, const short* __restrict__ Bt,
    const float* __restrict__ bias, float* __restrict__ outF) {
  __shared__ short As[128 * 64];
  __shared__ short Bs[128 * 64];
  int tid = threadIdx.x, w = tid >> 6, ln = tid & 63, lg = ln >> 4, lr = ln & 15;
  int m0 = blockIdx.x * 128, n0 = blockIdx.y * 128;
  int wr = w >> 1, wc = w & 1;
  f32x4 acc[4][4] = {};

  for (int k0 = 0; k0 < 1024; k0 += 64) {
    __syncthreads();
#pragma unroll
    for (int i = 0; i < 4; ++i) {
      int cb = w * 64 + i * 256;
      int c = cb + ln;
      GLD_LDS(A  + (size_t)(m0 + (c >> 3)) * 1024 + k0 + (c & 7) * 8, &As[cb * 8]);
      GLD_LDS(Bt + (size_t)(n0 + (c >> 3)) * 1024 + k0 + (c & 7) * 8, &Bs[cb * 8]);
    }
    __syncthreads();
#pragma unroll
    for (int kh = 0; kh < 2; ++kh) {
      bf16x8 af[4], bfr[4];
#pragma unroll
      for (int mi = 0; mi < 4; ++mi)
        af[mi] = *(const bf16x8*)&As[(wr * 64 + mi * 16 + lr) * 64 + kh * 32 + lg * 8];
#pragma unroll
      for (int ni = 0; ni < 4; ++ni)
        bfr[ni] = *(const bf16x8*)&Bs[(wc * 64 + ni * 16 + lr) * 64 + kh * 32 + lg * 8];
#pragma unroll
      for (int mi = 0; mi < 4; ++mi)
#pragma unroll
        for (int ni = 0; ni < 4; ++ni)
          acc[mi][ni] = MFMA16(af[mi], bfr[ni], acc[mi][ni]);
    }
  }

#pragma unroll
  for (int ni = 0; ni < 4; ++ni) {
    int n = n0 + wc * 64 + ni * 16 + lr;
    float bv = bias[n];
#pragma unroll
    for (int mi = 0; mi < 4; ++mi) {
      int mbase = m0 + wr * 64 + mi * 16 + 4 * lg;
#pragma unroll
      for (int r = 0; r < 4; ++r)
        outF[(size_t)(mbase + r) * 1024 + n] = acc[mi][ni][r] + bv;
    }
  }
}

// ---------------- per-row squared norms (pre-scaled by log2(e)^2) ----------------
__global__ __launch_bounds__(256) void norms_k(
    const short* __restrict__ Qm, const short* __restrict__ Qs,
    const short* __restrict__ Km, const short* __restrict__ Ks,
    float* __restrict__ sqq, float* __restrict__ sqk) {
  int id = blockIdx.x * 256 + threadIdx.x;  // 0..131071
  int row = id & 65535;
  const short* p1 = (id < 65536) ? Qm : Km;
  const short* p2 = (id < 65536) ? Qs : Ks;
  float* outp = (id < 65536) ? sqq : sqk;
  const uint4* a = (const uint4*)(p1 + (size_t)row * DK);
  const uint4* b = (const uint4*)(p2 + (size_t)row * DK);
  float s = 0.f;
#pragma unroll
  for (int i = 0; i < 8; ++i) {
    uint4 x = a[i], y = b[i];
    unsigned vx[4] = {x.x, x.y, x.z, x.w};
    unsigned vy[4] = {y.x, y.y, y.z, y.w};
#pragma unroll
    for (int j = 0; j < 4; ++j) {
      float l1 = b2f((unsigned short)(vx[j] & 0xffff)), h1 = b2f((unsigned short)(vx[j] >> 16));
      float l2 = b2f((unsigned short)(vy[j] & 0xffff)), h2 = b2f((unsigned short)(vy[j] >> 16));
      s += l1 * l1 + h1 * h1 + l2 * l2 + h2 * h2;
    }
  }
  outp[row] = s * L2E2;   // exp2-domain
}

// ---------------- fused Wasserstein attention: counted-vmcnt pipeline ----------------
// grid (8,32) = 256 blocks (1/CU), XCD-swizzled (FETCH 140->25MB proven R12).
// 512 threads = 8 waves, wave w owns 32 q-rows [q0 + 32w, +32), BQ=256.
// KT=32, FOUR 16KB LDS buffers (64KB total). Per tile (T3+T4):
//   s_waitcnt vmcnt(4)   <- tile t landed; t+1,t+2 stay IN FLIGHT (never 0)
//   s_barrier (raw, memory-clobbered asm: NO vmcnt0/lgkm0 drain)
//   issue tile t+3 into buf[(t+3)&3]  (safe: all waves' t-1 reads done)
//   compute tile t (QK 8xMFMA32, softmax, PV 8xMFMA32) with setprio (T5)
// Buffer layout (bytes): [0,4K) Km[32][64sh] | [4K,8K) Ks | [8K,16K) Vt[128][32sh]
// K swizzle (verified 0-conflict): read byte ^ ((krow&7)^((krow>>3)&3))<<4,
//   source col pre-swizzled (involution). V swizzle: byte ^ (((vrow>>1)&3))<<4
//   spreads 32 consecutive 64B rows across the full 128B line space.
// No k-split -> epilogue is a direct global write (no LDS scratch combine).
__global__ __launch_bounds__(512, 2) void attn_k(
    const short* __restrict__ Qm, const short* __restrict__ Km, const short* __restrict__ VmT,
    const short* __restrict__ Qs, const short* __restrict__ Ks, const short* __restrict__ VsT,
    const float* __restrict__ sqq, const float* __restrict__ sqk,
    short* __restrict__ Om, short* __restrict__ Os) {
  int id = blockIdx.y * 8 + blockIdx.x;   // gridDim (8,32)
  int pid = id >> 3;
  int bh = (id & 7) * 4 + (pid >> 3);     // XCD (id&7) owns 4 heads
  int q0 = (pid & 7) * 256;
  int tid = threadIdx.x, w = tid >> 6, ln = tid & 63;
  int l31 = ln & 31, h = ln >> 5;

  __shared__ __align__(16) char pool[65536];
  short* poolS = (short*)pool;

  const size_t bhQ = (size_t)bh * LSEQ * DK;

  // Q fragments (B operand: col = q = l31, k-dim d = dblk*16 + h*8 + j)
  int q = q0 + w * 32 + l31;
  bf16x8 qmf[4], qsf[4];
#pragma unroll
  for (int d = 0; d < 4; ++d) {
    qmf[d] = *(const bf16x8*)(Qm + bhQ + (size_t)q * DK + d * 16 + h * 8);
    qsf[d] = *(const bf16x8*)(Qs + bhQ + (size_t)q * DK + d * 16 + h * 8);
  }
  float sqQ = sqq[(size_t)bh * LSEQ + q];
  const float* sqkp = sqk + (size_t)bh * LSEQ;

  // staging sources: 2 x 16B loads per thread per tile.
  // load0: tids 0-255 -> Km rows 0-31 (8 slots), tids 256-511 -> Ks rows 0-31.
  // load1: all tids -> Vt rows 0-127 (4 slots of 8 shorts).
  const short* sb0;
  {
    int t2 = tid & 255;
    int rr = t2 >> 3;
    int cs = ((t2 & 7) ^ (rr & 7) ^ ((rr >> 3) & 3)) * 8;
    sb0 = ((tid < 256) ? Km : Ks) + bhQ + (size_t)rr * DK + cs;
  }
  const short* sb1;
  {
    int rv = tid >> 2, sv = tid & 3;
    int cs = (sv ^ ((rv >> 1) & 3)) * 8;
    sb1 = ((rv < 64) ? (VmT + ((size_t)bh * DK + rv) * LSEQ)
                     : (VsT + ((size_t)bh * DK + (rv - 64)) * LSEQ)) + cs;
  }

  f32x16 acc[4] = {};
  float prs = 0.f;

  const int krow = l31;
  const int kswz = ((krow & 7) ^ ((krow >> 3) & 3)) << 4;

  // prolog: issue tiles 0,1,2 into buffers 0,1,2 (6 loads in flight per wave)
#pragma unroll
  for (int p = 0; p < 3; ++p) {
    GLD_LDS(sb0 + (size_t)p * 2048, poolS + p * 8192 + w * 512);
    GLD_LDS(sb1 + (size_t)p * 32,   poolS + p * 8192 + 4096 + w * 512);
  }

  const int NT = LSEQ / 32;   // 64 tiles
  for (int t = 0; t < NT; ++t) {
    asm volatile("s_waitcnt vmcnt(4)" ::: "memory");   // tile t landed (own share)
    asm volatile("s_barrier" ::: "memory");            // all waves' shares landed
    {
      int tn = (t + 3 < NT) ? (t + 3) : (NT - 1);      // clamp: dead-writes safe
      int bn = (t + 3) & 3;
      GLD_LDS(sb0 + (size_t)tn * 2048, poolS + bn * 8192 + w * 512);
      GLD_LDS(sb1 + (size_t)tn * 32,   poolS + bn * 8192 + 4096 + w * 512);
    }
    const char* base = (const char*)(poolS + (t & 3) * 8192);

    // QK^T: S[k][q], 32 k x 32 q
    f32x16 sm = {}, ss = {};
    __builtin_amdgcn_s_setprio(1);
#pragma unroll
    for (int d = 0; d < 4; ++d) {
      bf16x8 am = *(const bf16x8*)(base + krow * 128 + ((d * 32 + h * 16) ^ kswz));
      bf16x8 as = *(const bf16x8*)(base + 4096 + krow * 128 + ((d * 32 + h * 16) ^ kswz));
      sm = MFMA32(am, qmf[d], sm);
      ss = MFMA32(as, qsf[d], ss);
    }
    __builtin_amdgcn_s_setprio(0);

    // softmax numerator (exp2-domain); S row k_local = (reg&3)+8*(reg>>2)+4*h
    float pv[16];
    int k0b = t * 32;
#pragma unroll
    for (int rq = 0; rq < 4; ++rq) {
      f32x4 rsk = *(const f32x4*)&sqkp[k0b + 8 * rq + 4 * h];
#pragma unroll
      for (int r = 0; r < 4; ++r) {
        int i = rq * 4 + r;
        float w2 = fmaf(-2.f * L2E2, sm[i] + ss[i], sqQ + rsk[r]);  // = L2E2*wd^2
        float wdp = __builtin_amdgcn_sqrtf(fmaxf(w2, 0.f));         // = L2E*wd
        float sim = fexp2n(wdp);                                    // = exp(-wd)
        float p = fexp2(sim * L2E);                                 // = exp(sim)
        prs += p;
        pv[i] = p;
      }
    }
    // pack to bf16 + lane-half swap -> PV B-frags (k 0..15 -> f0, 16..31 -> f1)
    unsigned u0 = pk2c(pv[0], pv[1]),   u1 = pk2c(pv[2], pv[3]);
    unsigned u2 = pk2c(pv[4], pv[5]),   u3 = pk2c(pv[6], pv[7]);
    unsigned u4 = pk2c(pv[8], pv[9]),   u5 = pk2c(pv[10], pv[11]);
    unsigned u6 = pk2c(pv[12], pv[13]), u7 = pk2c(pv[14], pv[15]);
    asm volatile("v_permlane32_swap_b32 %0, %1" : "+v"(u0), "+v"(u2));
    asm volatile("v_permlane32_swap_b32 %0, %1" : "+v"(u1), "+v"(u3));
    asm volatile("v_permlane32_swap_b32 %0, %1" : "+v"(u4), "+v"(u6));
    asm volatile("v_permlane32_swap_b32 %0, %1" : "+v"(u5), "+v"(u7));
    union { uint4 u; bf16x8 v; } f0, f1;
    f0.u.x = u0; f0.u.y = u1; f0.u.z = u2; f0.u.w = u3;
    f1.u.x = u4; f1.u.y = u5; f1.u.z = u6; f1.u.w = u7;

    // PV: acc[vblk] += V-frag(32v x 16k) x P-frag
    __builtin_amdgcn_s_setprio(1);
#pragma unroll
    for (int vblk = 0; vblk < 4; ++vblk) {
      int vrow = vblk * 32 + l31;
      int vswz = ((vrow >> 1) & 3) << 4;
      const char* vbase = base + 8192 + vrow * 64;
      bf16x8 v0 = *(const bf16x8*)(vbase + ((h * 16) ^ vswz));
      bf16x8 v1 = *(const bf16x8*)(vbase + ((32 + h * 16) ^ vswz));
      acc[vblk] = MFMA32(v0, f0.v, acc[vblk]);
      acc[vblk] = MFMA32(v1, f1.v, acc[vblk]);
    }
    __builtin_amdgcn_s_setprio(0);
  }

  // drain remaining DMA before epilogue (protect next block's LDS)
  asm volatile("s_waitcnt vmcnt(0)" ::: "memory");

  // row-sum: reduce over lane halves (h split of k-rows)
  prs += __shfl_xor(prs, 32);
  float inv = 1.f / prs;

  int b = bh >> 4, hh = bh & 15;
  size_t orow = ((size_t)(b * LSEQ + q)) * DMODEL + hh * DK;
#pragma unroll
  for (int vblk = 0; vblk < 4; ++vblk) {
    short* obuf = (vblk < 2) ? Om : Os;
    int vbase = (vblk & 1) * 32 + 4 * h;
#pragma unroll
    for (int rq = 0; rq < 4; ++rq) {
      float o0 = acc[vblk][rq * 4 + 0] * inv;
      float o1 = acc[vblk][rq * 4 + 1] * inv;
      float o2 = acc[vblk][rq * 4 + 2] * inv;
      float o3 = acc[vblk][rq * 4 + 3] * inv;
      uint2 pk; pk.x = pk2c(o0, o1); pk.y = pk2c(o2, o3);
      *(uint2*)(obuf + orow + vbase + 8 * rq) = pk;
    }
  }
}

extern "C" void kernel_launch(void* const* d_in, const int* in_sizes, int n_in,
                              void* d_out, int out_size, void* d_ws, size_t ws_size,
                              hipStream_t stream) {
  const float* mu    = (const float*)d_in[0];
  const float* sigma = (const float*)d_in[1];
  const float* Wqm   = (const float*)d_in[2];
  const float* bqm   = (const float*)d_in[3];
  const float* Wqs   = (const float*)d_in[4];
  const float* bqs   = (const float*)d_in[5];
  const float* Wo    = (const float*)d_in[6];
  const float* bo    = (const float*)d_in[7];
  float* out = (float*)d_out;
  char* ws = (char*)d_ws;
  const size_t MB = 1u << 20;

  short* Amu   = (short*)(ws + 0);        // 8MB, reused as Om
  short* Asg   = (short*)(ws + 8 * MB);   // 8MB, reused as Os (contiguous with Om)
  short* Wqm_t = (short*)(ws + 16 * MB);  // 6MB
  short* Wqs_t = (short*)(ws + 22 * MB);  // 6MB
  short* Wo_t  = (short*)(ws + 28 * MB);  // 2MB
  short* Qm    = (short*)(ws + 30 * MB);  // 8MB each below
  short* Km    = (short*)(ws + 38 * MB);
  short* VmT   = (short*)(ws + 46 * MB);
  short* Qs    = (short*)(ws + 54 * MB);
  short* Ks    = (short*)(ws + 62 * MB);
  short* VsT   = (short*)(ws + 70 * MB);
  float* sqq   = (float*)(ws + 78 * MB);            // 256KB
  float* sqk   = (float*)(ws + 78 * MB + 256 * 1024);
  short* Om = Amu;
  short* Os = Asg;

  cvt2_k<<<2048, 256, 0, stream>>>(mu, sigma, Amu, Asg, MTOT * DMODEL / 8);
  cvt_tr_all_k<<<7168, 256, 0, stream>>>(Wqm, Wqs, Wo, Wqm_t, Wqs_t, Wo_t);

  qkv_gemm_k<<<dim3(32, 48), 256, 0, stream>>>(Amu, Asg, Wqm_t, Wqs_t, bqm, bqs,
                                               Qm, Km, VmT, Qs, Ks, VsT);

  norms_k<<<512, 256, 0, stream>>>(Qm, Qs, Km, Ks, sqq, sqk);

  attn_k<<<dim3(8, 32), 512, 0, stream>>>(Qm, Km, VmT, Qs, Ks, VsT, sqq, sqk, Om, Os);

  // out-proj for mu and sigma as ONE GEMM (Om|Os contiguous, M=8192)
  gemm128_k<<<dim3(64, 8), 256, 0, stream>>>(Om, Wo_t, bo, out);
}

// Round 14
// 234.056 us; speedup vs baseline: 2.5117x; 1.1081x over previous
//
#include <hip/hip_runtime.h>
#include <hip/hip_bf16.h>

#define LSEQ   2048
#define DK     64
#define NH     16
#define BS     2
#define DMODEL 1024
#define BH     (BS*NH)    // 32
#define MTOT   (BS*LSEQ)  // 4096

typedef __attribute__((ext_vector_type(8))) short bf16x8;
typedef __attribute__((ext_vector_type(4))) float f32x4;
typedef __attribute__((ext_vector_type(16))) float f32x16;

#define MFMA16(a,b,c) __builtin_amdgcn_mfma_f32_16x16x32_bf16((a),(b),(c),0,0,0)
#define MFMA32(a,b,c) __builtin_amdgcn_mfma_f32_32x32x16_bf16((a),(b),(c),0,0,0)
#define GLD_LDS(g,l) __builtin_amdgcn_global_load_lds((const __attribute__((address_space(1))) void*)(g), (__attribute__((address_space(3))) void*)(l), 16, 0, 0)

#define L2E   1.4426950408889634f      // log2(e)
#define L2E2  2.0813689810056077f      // log2(e)^2

__device__ __forceinline__ short f2bs(float f) {
  union { __hip_bfloat16 h; short s; } u; u.h = __float2bfloat16(f); return u.s;
}
__device__ __forceinline__ float b2f(unsigned short s) {
  union { unsigned u; float f; } v; v.u = ((unsigned)s) << 16; return v.f;
}
// cheap round-half-up bf16 (inputs guaranteed finite)
__device__ __forceinline__ unsigned short f2bs_c(float f) {
  union { float f; unsigned u; } v; v.f = f;
  return (unsigned short)((v.u + 0x8000u) >> 16);
}
__device__ __forceinline__ unsigned pk2c(float lo, float hi) {
  union { float f; unsigned u; } a, b; a.f = lo; b.f = hi;
  return ((a.u + 0x8000u) >> 16) | ((b.u + 0x8000u) & 0xffff0000u);
}
__device__ __forceinline__ unsigned pk2(float lo, float hi) {
  return (unsigned)(unsigned short)f2bs(lo) | (((unsigned)(unsigned short)f2bs(hi)) << 16);
}
// raw v_exp_f32 (2^x); VALU->VALU deps are HW-interlocked on CDNA
__device__ __forceinline__ float fexp2(float x) {
  float r; asm("v_exp_f32 %0, %1" : "=v"(r) : "v"(x)); return r;
}
__device__ __forceinline__ float fexp2n(float x) {   // 2^(-x), free input modifier
  float r; asm("v_exp_f32 %0, -%1" : "=v"(r) : "v"(x)); return r;
}
// single-instruction packed f32->bf16 (RNE) -- replaces pk2c in the hot loop
__device__ __forceinline__ unsigned cvtpk(float lo, float hi) {
  unsigned r; asm("v_cvt_pk_bf16_f32 %0, %1, %2" : "=v"(r) : "v"(lo), "v"(hi)); return r;
}

// ---------------- f32 -> bf16 flat convert, mu AND sigma in one launch ----------------
__global__ __launch_bounds__(256) void cvt2_k(const float* __restrict__ a,
                                              const float* __restrict__ b,
                                              short* __restrict__ oa,
                                              short* __restrict__ ob, int n8) {
  int total = n8 * 2;
  for (int i = blockIdx.x * blockDim.x + threadIdx.x; i < total; i += gridDim.x * blockDim.x) {
    int sel = i >= n8;
    int j = sel ? i - n8 : i;
    const float4* p = (const float4*)(sel ? b : a) + (size_t)j * 2;
    float4 x = p[0], y = p[1];
    uint4 o;
    o.x = pk2(x.x, x.y); o.y = pk2(x.z, x.w);
    o.z = pk2(y.x, y.y); o.w = pk2(y.z, y.w);
    ((uint4*)(sel ? ob : oa))[j] = o;
  }
}

// ---------------- all three weight transposes (f32 [K][N] -> bf16 [N][K]) ----------------
__global__ __launch_bounds__(256) void cvt_tr_all_k(
    const float* __restrict__ Wqm, const float* __restrict__ Wqs, const float* __restrict__ Wo,
    short* __restrict__ Wqm_t, short* __restrict__ Wqs_t, short* __restrict__ Wo_t) {
  __shared__ float tile[32][33];
  int id = blockIdx.x;
  const float* W; short* Wt; int Ncols, bx;
  if (id < 3072)      { W = Wqm; Wt = Wqm_t; Ncols = 3072; bx = id % 96; id /= 96; }
  else if (id < 6144) { id -= 3072; W = Wqs; Wt = Wqs_t; Ncols = 3072; bx = id % 96; id /= 96; }
  else                { id -= 6144; W = Wo;  Wt = Wo_t;  Ncols = 1024; bx = id % 32; id /= 32; }
  int n0 = bx * 32, k0 = id * 32;
  int t = threadIdx.x;
#pragma unroll
  for (int i = 0; i < 4; ++i) {
    int idx = t + i * 256; int r = idx >> 5, c = idx & 31;
    tile[r][c] = W[(size_t)(k0 + r) * Ncols + n0 + c];
  }
  __syncthreads();
#pragma unroll
  for (int i = 0; i < 4; ++i) {
    int idx = t + i * 256; int r = idx >> 5, c = idx & 31;
    Wt[(size_t)(n0 + r) * 1024 + k0 + c] = f2bs(tile[c][r]);
  }
}

// ---------------- fused QKV GEMM (mu + sigma in ONE dispatch), 128x128 tile ----------------
__global__ __launch_bounds__(256) void qkv_gemm_k(
    const short* __restrict__ Amu, const short* __restrict__ Asg,
    const short* __restrict__ Wqm_t, const short* __restrict__ Wqs_t,
    const float* __restrict__ bqm, const float* __restrict__ bqs,
    short* __restrict__ Qm, short* __restrict__ Km, short* __restrict__ VmT,
    short* __restrict__ Qs, short* __restrict__ Ks, short* __restrict__ VsT) {
  __shared__ short As[128 * 64];
  __shared__ short Bs[128 * 64];
  int ny = blockIdx.y;                 // 0..47; >=24 -> sigma set
  int sg = ny >= 24;
  int n0 = (sg ? ny - 24 : ny) * 128;
  const short* A  = sg ? Asg : Amu;
  const short* Bt = sg ? Wqs_t : Wqm_t;
  const float* bias = sg ? bqs : bqm;
  short* Qb  = sg ? Qs : Qm;
  short* Kb  = sg ? Ks : Km;
  short* VTb = sg ? VsT : VmT;

  int tid = threadIdx.x, w = tid >> 6, ln = tid & 63, lg = ln >> 4, lr = ln & 15;
  int m0 = blockIdx.x * 128;
  int wr = w >> 1, wc = w & 1;
  f32x4 acc[4][4] = {};

  for (int k0 = 0; k0 < 1024; k0 += 64) {
    __syncthreads();
#pragma unroll
    for (int i = 0; i < 4; ++i) {
      int cb = w * 64 + i * 256;
      int c = cb + ln;
      GLD_LDS(A  + (size_t)(m0 + (c >> 3)) * 1024 + k0 + (c & 7) * 8, &As[cb * 8]);
      GLD_LDS(Bt + (size_t)(n0 + (c >> 3)) * 1024 + k0 + (c & 7) * 8, &Bs[cb * 8]);
    }
    __syncthreads();
#pragma unroll
    for (int kh = 0; kh < 2; ++kh) {
      bf16x8 af[4], bfr[4];
#pragma unroll
      for (int mi = 0; mi < 4; ++mi)
        af[mi] = *(const bf16x8*)&As[(wr * 64 + mi * 16 + lr) * 64 + kh * 32 + lg * 8];
#pragma unroll
      for (int ni = 0; ni < 4; ++ni)
        bfr[ni] = *(const bf16x8*)&Bs[(wc * 64 + ni * 16 + lr) * 64 + kh * 32 + lg * 8];
#pragma unroll
      for (int mi = 0; mi < 4; ++mi)
#pragma unroll
        for (int ni = 0; ni < 4; ++ni)
          acc[mi][ni] = MFMA16(af[mi], bfr[ni], acc[mi][ni]);
    }
  }

#pragma unroll
  for (int ni = 0; ni < 4; ++ni) {
    int n = n0 + wc * 64 + ni * 16 + lr;
    float bv = bias[n];
    int part = n >> 10, cc = n & 1023, hh = cc >> 6, dd = cc & 63;
#pragma unroll
    for (int mi = 0; mi < 4; ++mi) {
      int mbase = m0 + wr * 64 + mi * 16 + 4 * lg;
      float vv[4];
#pragma unroll
      for (int r = 0; r < 4; ++r) vv[r] = acc[mi][ni][r] + bv;
      if (part == 2) {
        int b = mbase >> 11, tok = mbase & 2047, bh = b * NH + hh;
        uint2 pk; pk.x = pk2c(vv[0], vv[1]); pk.y = pk2c(vv[2], vv[3]);
        *(uint2*)&VTb[((size_t)bh * DK + dd) * LSEQ + tok] = pk;
      } else {
        short* dst = (part == 0) ? Qb : Kb;
#pragma unroll
        for (int r = 0; r < 4; ++r) {
          int m = mbase + r;
          int b = m >> 11, tok = m & 2047, bh = b * NH + hh;
          dst[((size_t)bh * LSEQ + tok) * DK + dd] = (short)f2bs_c(vv[r]);
        }
      }
    }
  }
}

// ---------------- 128x128-tile bf16 GEMM (out-proj, f32 out) ----------------
__global__ __launch_bounds__(256) void gemm128_k(
    const short* __restrict__ A, const short* __restrict__ Bt,
    const float* __restrict__ bias, float* __restrict__ outF) {
  __shared__ short As[128 * 64];
  __shared__ short Bs[128 * 64];
  int tid = threadIdx.x, w = tid >> 6, ln = tid & 63, lg = ln >> 4, lr = ln & 15;
  int m0 = blockIdx.x * 128, n0 = blockIdx.y * 128;
  int wr = w >> 1, wc = w & 1;
  f32x4 acc[4][4] = {};

  for (int k0 = 0; k0 < 1024; k0 += 64) {
    __syncthreads();
#pragma unroll
    for (int i = 0; i < 4; ++i) {
      int cb = w * 64 + i * 256;
      int c = cb + ln;
      GLD_LDS(A  + (size_t)(m0 + (c >> 3)) * 1024 + k0 + (c & 7) * 8, &As[cb * 8]);
      GLD_LDS(Bt + (size_t)(n0 + (c >> 3)) * 1024 + k0 + (c & 7) * 8, &Bs[cb * 8]);
    }
    __syncthreads();
#pragma unroll
    for (int kh = 0; kh < 2; ++kh) {
      bf16x8 af[4], bfr[4];
#pragma unroll
      for (int mi = 0; mi < 4; ++mi)
        af[mi] = *(const bf16x8*)&As[(wr * 64 + mi * 16 + lr) * 64 + kh * 32 + lg * 8];
#pragma unroll
      for (int ni = 0; ni < 4; ++ni)
        bfr[ni] = *(const bf16x8*)&Bs[(wc * 64 + ni * 16 + lr) * 64 + kh * 32 + lg * 8];
#pragma unroll
      for (int mi = 0; mi < 4; ++mi)
#pragma unroll
        for (int ni = 0; ni < 4; ++ni)
          acc[mi][ni] = MFMA16(af[mi], bfr[ni], acc[mi][ni]);
    }
  }

#pragma unroll
  for (int ni = 0; ni < 4; ++ni) {
    int n = n0 + wc * 64 + ni * 16 + lr;
    float bv = bias[n];
#pragma unroll
    for (int mi = 0; mi < 4; ++mi) {
      int mbase = m0 + wr * 64 + mi * 16 + 4 * lg;
#pragma unroll
      for (int r = 0; r < 4; ++r)
        outF[(size_t)(mbase + r) * 1024 + n] = acc[mi][ni][r] + bv;
    }
  }
}

// ---------------- per-row squared norms (pre-scaled by log2(e)^2) ----------------
__global__ __launch_bounds__(256) void norms_k(
    const short* __restrict__ Qm, const short* __restrict__ Qs,
    const short* __restrict__ Km, const short* __restrict__ Ks,
    float* __restrict__ sqq, float* __restrict__ sqk) {
  int id = blockIdx.x * 256 + threadIdx.x;  // 0..131071
  int row = id & 65535;
  const short* p1 = (id < 65536) ? Qm : Km;
  const short* p2 = (id < 65536) ? Qs : Ks;
  float* outp = (id < 65536) ? sqq : sqk;
  const uint4* a = (const uint4*)(p1 + (size_t)row * DK);
  const uint4* b = (const uint4*)(p2 + (size_t)row * DK);
  float s = 0.f;
#pragma unroll
  for (int i = 0; i < 8; ++i) {
    uint4 x = a[i], y = b[i];
    unsigned vx[4] = {x.x, x.y, x.z, x.w};
    unsigned vy[4] = {y.x, y.y, y.z, y.w};
#pragma unroll
    for (int j = 0; j < 4; ++j) {
      float l1 = b2f((unsigned short)(vx[j] & 0xffff)), h1 = b2f((unsigned short)(vx[j] >> 16));
      float l2 = b2f((unsigned short)(vy[j] & 0xffff)), h2 = b2f((unsigned short)(vy[j] >> 16));
      s += l1 * l1 + h1 * h1 + l2 * l2 + h2 * h2;
    }
  }
  outp[row] = s * L2E2;   // exp2-domain
}

// ---------------- fused Wasserstein attention: T15 software pipeline ----------------
// grid (8,32) = 256 blocks (1/CU), XCD-swizzled. 512 threads = 8 waves,
// wave w owns 32 q-rows, BQ=256. KT=32, FOUR 16KB LDS buffers.
// T15: each iteration t runs QK(t) [MFMA] then softmax(t-1)+PV(t-1)
// [VALU/trans + MFMA] -- softmax has NO dep on the in-flight QK, so the
// wave issues VALU under MFMA execution (de-serializes the pipes that
// R13's counters showed summing to ~100%).
// Merged S accumulator: mfma(Km,Qm)+mfma(Ks,Qs) chain into ONE f32x16
// (cross term = QmKm + QsKs). cvt_pk_bf16_f32 for P packing.
// V layout: combined 128B rows [64r][Vm 64B | Vs 64B], XOR-8 col swizzle
// (the R8-12 proven zero-conflict geometry; R13's 64B V rows were
// structurally conflicted). K layout unchanged from R13 (0-conflict).
// Schedule: per tile: vmcnt(6) [tile t landed; t+1 stays in flight],
// barrier, issue t+2, QK(t), softmax(t-1), rsk(t) prefetch, PV(t-1).
// Per-step VMEM = 2 DMA + 4 rsk = 6 -> vmcnt(6) counting exact.
__global__ __launch_bounds__(512, 2) void attn_k(
    const short* __restrict__ Qm, const short* __restrict__ Km, const short* __restrict__ VmT,
    const short* __restrict__ Qs, const short* __restrict__ Ks, const short* __restrict__ VsT,
    const float* __restrict__ sqq, const float* __restrict__ sqk,
    short* __restrict__ Om, short* __restrict__ Os) {
  int id = blockIdx.y * 8 + blockIdx.x;   // gridDim (8,32)
  int pid = id >> 3;
  int bh = (id & 7) * 4 + (pid >> 3);     // XCD (id&7) owns 4 heads
  int q0 = (pid & 7) * 256;
  int tid = threadIdx.x, w = tid >> 6, ln = tid & 63;
  int l31 = ln & 31, h = ln >> 5;

  // per 16KB buffer: [0,4K) Km[32r][128B,XOR8] | [4K,8K) Ks | [8K,16K) V[64r][128B,XOR8]
  __shared__ __align__(16) char pool[65536];
  short* poolS = (short*)pool;

  const size_t bhQ = (size_t)bh * LSEQ * DK;

  // Q fragments (B operand: col = q = l31, k-dim d = dblk*16 + h*8 + j)
  int q = q0 + w * 32 + l31;
  bf16x8 qmf[4], qsf[4];
#pragma unroll
  for (int d = 0; d < 4; ++d) {
    qmf[d] = *(const bf16x8*)(Qm + bhQ + (size_t)q * DK + d * 16 + h * 8);
    qsf[d] = *(const bf16x8*)(Qs + bhQ + (size_t)q * DK + d * 16 + h * 8);
  }
  float sqQ = sqq[(size_t)bh * LSEQ + q];
  const float* sqkp = sqk + (size_t)bh * LSEQ;

  // K DMA source (as R13, proven 0-conflict): per tile stride 32*DK shorts
  const short* sb0;
  {
    int t2 = tid & 255;
    int rr = t2 >> 3;
    int cs = ((t2 & 7) ^ (rr & 7) ^ ((rr >> 3) & 3)) * 8;
    sb0 = ((tid < 256) ? Km : Ks) + bhQ + (size_t)rr * DK + cs;
  }
  // V DMA source: combined row = tid>>3 (0..63), slot c' = tid&7,
  // global col c = c' ^ (row&7); c<4 -> Vm col c, c>=4 -> Vs col c-4.
  const short* sb1;
  {
    int row = tid >> 3;
    int c = (tid & 7) ^ (row & 7);
    sb1 = ((c < 4) ? (VmT + ((size_t)bh * DK + row) * LSEQ + c * 8)
                   : (VsT + ((size_t)bh * DK + row) * LSEQ + (c - 4) * 8));
  }

  f32x16 acc[4] = {};
  float prs = 0.f;

  const int krow = l31;
  const int kswz = ((krow & 7) ^ ((krow >> 3) & 3)) << 4;
  const int NT = LSEQ / 32;   // 64 tiles

#define ISSUE_TILE(tt, bb) do {                                          \
    GLD_LDS(sb0 + (size_t)(tt) * 2048, poolS + (bb) * 8192 + w * 512);   \
    GLD_LDS(sb1 + (size_t)(tt) * 32,   poolS + (bb) * 8192 + 4096 + w * 512); \
  } while (0)

  // QK of tile tt from buffer bb -> f32x16 (merged mu+sigma accumulator)
#define QK_TILE(bb, sdst) do {                                           \
    const char* kb_ = (const char*)(poolS + (bb) * 8192);                \
    __builtin_amdgcn_s_setprio(1);                                       \
    _Pragma("unroll")                                                    \
    for (int d = 0; d < 4; ++d) {                                        \
      bf16x8 am = *(const bf16x8*)(kb_ + krow * 128 + ((d * 32 + h * 16) ^ kswz)); \
      sdst = MFMA32(am, qmf[d], sdst);                                   \
      bf16x8 as = *(const bf16x8*)(kb_ + 4096 + krow * 128 + ((d * 32 + h * 16) ^ kswz)); \
      sdst = MFMA32(as, qsf[d], sdst);                                   \
    }                                                                    \
    __builtin_amdgcn_s_setprio(0);                                       \
  } while (0)

  // prolog: issue tiles 0,1; land tile 0; issue tile 2; QK(0); rsk(0)
  ISSUE_TILE(0, 0);
  ISSUE_TILE(1, 1);
  asm volatile("s_waitcnt vmcnt(2)" ::: "memory");
  asm volatile("s_barrier" ::: "memory");
  ISSUE_TILE(2, 2);

  f32x16 s_prev = {};
  QK_TILE(0, s_prev);
  f32x4 rskreg[4];
#pragma unroll
  for (int rq = 0; rq < 4; ++rq)
    rskreg[rq] = *(const f32x4*)&sqkp[8 * rq + 4 * h];

  for (int t = 1; t < NT; ++t) {
    asm volatile("s_waitcnt vmcnt(6)" ::: "memory");   // tile t landed; t+1 in flight
    asm volatile("s_barrier" ::: "memory");            // all waves' tile t landed
    {
      int tn = (t + 2 < NT) ? (t + 2) : (NT - 1);      // clamped dead-writes safe
      ISSUE_TILE(tn, (t + 2) & 3);
    }

    // QK(t) -> s_cur (MFMA pipe; softmax below overlaps its execution)
    f32x16 s_cur = {};
    QK_TILE(t & 3, s_cur);

    // softmax of tile t-1 (VALU/trans; independent of QK(t))
    float pv[16];
#pragma unroll
    for (int rq = 0; rq < 4; ++rq) {
#pragma unroll
      for (int r = 0; r < 4; ++r) {
        int i = rq * 4 + r;
        float w2 = fmaf(-2.f * L2E2, s_prev[i], sqQ + rskreg[rq][r]);
        float wdp = __builtin_amdgcn_sqrtf(fmaxf(w2, 0.f));
        float sim = fexp2n(wdp);
        float p = fexp2(sim * L2E);
        prs += p;
        pv[i] = p;
      }
    }
    unsigned u0 = cvtpk(pv[0], pv[1]),   u1 = cvtpk(pv[2], pv[3]);
    unsigned u2 = cvtpk(pv[4], pv[5]),   u3 = cvtpk(pv[6], pv[7]);
    unsigned u4 = cvtpk(pv[8], pv[9]),   u5 = cvtpk(pv[10], pv[11]);
    unsigned u6 = cvtpk(pv[12], pv[13]), u7 = cvtpk(pv[14], pv[15]);
    asm volatile("v_permlane32_swap_b32 %0, %1" : "+v"(u0), "+v"(u2));
    asm volatile("v_permlane32_swap_b32 %0, %1" : "+v"(u1), "+v"(u3));
    asm volatile("v_permlane32_swap_b32 %0, %1" : "+v"(u4), "+v"(u6));
    asm volatile("v_permlane32_swap_b32 %0, %1" : "+v"(u5), "+v"(u7));
    union { uint4 u; bf16x8 v; } f0, f1;
    f0.u.x = u0; f0.u.y = u1; f0.u.z = u2; f0.u.w = u3;
    f1.u.x = u4; f1.u.y = u5; f1.u.z = u6; f1.u.w = u7;

    // prefetch rsk for tile t (consumed next iteration) -- fixed VMEM count
#pragma unroll
    for (int rq = 0; rq < 4; ++rq)
      rskreg[rq] = *(const f32x4*)&sqkp[t * 32 + 8 * rq + 4 * h];

    // PV of tile t-1: acc[vblk] += V-frag x P-frag
    {
      const char* vb = (const char*)(poolS + ((t - 1) & 3) * 8192) + 8192;
      __builtin_amdgcn_s_setprio(1);
#pragma unroll
      for (int vblk = 0; vblk < 4; ++vblk) {
        int row = (vblk & 1) * 32 + l31;
        int cb = (vblk >> 1) * 4;
        int sw = row & 7;
        const char* rb = vb + row * 128;
        bf16x8 v0 = *(const bf16x8*)(rb + (((cb + h) ^ sw) << 4));
        bf16x8 v1 = *(const bf16x8*)(rb + (((cb + 2 + h) ^ sw) << 4));
        acc[vblk] = MFMA32(v0, f0.v, acc[vblk]);
        acc[vblk] = MFMA32(v1, f1.v, acc[vblk]);
      }
      __builtin_amdgcn_s_setprio(0);
    }

    s_prev = s_cur;
  }

  asm volatile("s_waitcnt vmcnt(0)" ::: "memory");   // drain clamped DMAs

  // tail: softmax + PV of tile NT-1 (rskreg holds rsk(NT-1))
  {
    float pv[16];
#pragma unroll
    for (int rq = 0; rq < 4; ++rq) {
#pragma unroll
      for (int r = 0; r < 4; ++r) {
        int i = rq * 4 + r;
        float w2 = fmaf(-2.f * L2E2, s_prev[i], sqQ + rskreg[rq][r]);
        float wdp = __builtin_amdgcn_sqrtf(fmaxf(w2, 0.f));
        float sim = fexp2n(wdp);
        float p = fexp2(sim * L2E);
        prs += p;
        pv[i] = p;
      }
    }
    unsigned u0 = cvtpk(pv[0], pv[1]),   u1 = cvtpk(pv[2], pv[3]);
    unsigned u2 = cvtpk(pv[4], pv[5]),   u3 = cvtpk(pv[6], pv[7]);
    unsigned u4 = cvtpk(pv[8], pv[9]),   u5 = cvtpk(pv[10], pv[11]);
    unsigned u6 = cvtpk(pv[12], pv[13]), u7 = cvtpk(pv[14], pv[15]);
    asm volatile("v_permlane32_swap_b32 %0, %1" : "+v"(u0), "+v"(u2));
    asm volatile("v_permlane32_swap_b32 %0, %1" : "+v"(u1), "+v"(u3));
    asm volatile("v_permlane32_swap_b32 %0, %1" : "+v"(u4), "+v"(u6));
    asm volatile("v_permlane32_swap_b32 %0, %1" : "+v"(u5), "+v"(u7));
    union { uint4 u; bf16x8 v; } f0, f1;
    f0.u.x = u0; f0.u.y = u1; f0.u.z = u2; f0.u.w = u3;
    f1.u.x = u4; f1.u.y = u5; f1.u.z = u6; f1.u.w = u7;

    const char* vb = (const char*)(poolS + ((NT - 1) & 3) * 8192) + 8192;
#pragma unroll
    for (int vblk = 0; vblk < 4; ++vblk) {
      int row = (vblk & 1) * 32 + l31;
      int cb = (vblk >> 1) * 4;
      int sw = row & 7;
      const char* rb = vb + row * 128;
      bf16x8 v0 = *(const bf16x8*)(rb + (((cb + h) ^ sw) << 4));
      bf16x8 v1 = *(const bf16x8*)(rb + (((cb + 2 + h) ^ sw) << 4));
      acc[vblk] = MFMA32(v0, f0.v, acc[vblk]);
      acc[vblk] = MFMA32(v1, f1.v, acc[vblk]);
    }
  }

  // row-sum: reduce over lane halves (h split of k-rows)
  prs += __shfl_xor(prs, 32);
  float inv = 1.f / prs;

  int b = bh >> 4, hh = bh & 15;
  size_t orow = ((size_t)(b * LSEQ + q)) * DMODEL + hh * DK;
#pragma unroll
  for (int vblk = 0; vblk < 4; ++vblk) {
    short* obuf = (vblk < 2) ? Om : Os;
    int vbase = (vblk & 1) * 32 + 4 * h;
#pragma unroll
    for (int rq = 0; rq < 4; ++rq) {
      float o0 = acc[vblk][rq * 4 + 0] * inv;
      float o1 = acc[vblk][rq * 4 + 1] * inv;
      float o2 = acc[vblk][rq * 4 + 2] * inv;
      float o3 = acc[vblk][rq * 4 + 3] * inv;
      uint2 pk; pk.x = pk2c(o0, o1); pk.y = pk2c(o2, o3);
      *(uint2*)(obuf + orow + vbase + 8 * rq) = pk;
    }
  }
#undef ISSUE_TILE
#undef QK_TILE
}

extern "C" void kernel_launch(void* const* d_in, const int* in_sizes, int n_in,
                              void* d_out, int out_size, void* d_ws, size_t ws_size,
                              hipStream_t stream) {
  const float* mu    = (const float*)d_in[0];
  const float* sigma = (const float*)d_in[1];
  const float* Wqm   = (const float*)d_in[2];
  const float* bqm   = (const float*)d_in[3];
  const float* Wqs   = (const float*)d_in[4];
  const float* bqs   = (const float*)d_in[5];
  const float* Wo    = (const float*)d_in[6];
  const float* bo    = (const float*)d_in[7];
  float* out = (float*)d_out;
  char* ws = (char*)d_ws;
  const size_t MB = 1u << 20;

  short* Amu   = (short*)(ws + 0);        // 8MB, reused as Om
  short* Asg   = (short*)(ws + 8 * MB);   // 8MB, reused as Os (contiguous with Om)
  short* Wqm_t = (short*)(ws + 16 * MB);  // 6MB
  short* Wqs_t = (short*)(ws + 22 * MB);  // 6MB
  short* Wo_t  = (short*)(ws + 28 * MB);  // 2MB
  short* Qm    = (short*)(ws + 30 * MB);  // 8MB each below
  short* Km    = (short*)(ws + 38 * MB);
  short* VmT   = (short*)(ws + 46 * MB);
  short* Qs    = (short*)(ws + 54 * MB);
  short* Ks    = (short*)(ws + 62 * MB);
  short* VsT   = (short*)(ws + 70 * MB);
  float* sqq   = (float*)(ws + 78 * MB);            // 256KB
  float* sqk   = (float*)(ws + 78 * MB + 256 * 1024);
  short* Om = Amu;
  short* Os = Asg;

  cvt2_k<<<2048, 256, 0, stream>>>(mu, sigma, Amu, Asg, MTOT * DMODEL / 8);
  cvt_tr_all_k<<<7168, 256, 0, stream>>>(Wqm, Wqs, Wo, Wqm_t, Wqs_t, Wo_t);

  qkv_gemm_k<<<dim3(32, 48), 256, 0, stream>>>(Amu, Asg, Wqm_t, Wqs_t, bqm, bqs,
                                               Qm, Km, VmT, Qs, Ks, VsT);

  norms_k<<<512, 256, 0, stream>>>(Qm, Qs, Km, Ks, sqq, sqk);

  attn_k<<<dim3(8, 32), 512, 0, stream>>>(Qm, Km, VmT, Qs, Ks, VsT, sqq, sqk, Om, Os);

  // out-proj for mu and sigma as ONE GEMM (Om|Os contiguous, M=8192)
  gemm128_k<<<dim3(64, 8), 256, 0, stream>>>(Om, Wo_t, bo, out);
}